// Round 3
// baseline (10569.379 us; speedup 1.0000x reference)
//
#include <hip/hip_runtime.h>
#include <hip/hip_bf16.h>
#include <stdint.h>

// Problem constants (fixed by the reference): B=64, L=4, H=1024, T=128.
#define NB   64
#define NH   1024
#define NL   4
#define NT   128

using bf16x8 = __attribute__((ext_vector_type(8))) short;  // 8 bf16 in 4 VGPRs
using f32x4  = __attribute__((ext_vector_type(4))) float;

// Split fp32 v into hi+lo bf16 (RNE). v ~= hi + lo with residual ~2^-17 * |v|.
__device__ __forceinline__ void split_bf16(float v, unsigned short& hi, unsigned short& lo) {
    unsigned u = __float_as_uint(v);
    unsigned short h = (unsigned short)((u + 0x7FFFu + ((u >> 16) & 1u)) >> 16);
    float hf = __uint_as_float((unsigned)h << 16);
    float r  = v - hf;
    unsigned ur = __float_as_uint(r);
    unsigned short l = (unsigned short)((ur + 0x7FFFu + ((ur >> 16) & 1u)) >> 16);
    hi = h; lo = l;
}

// A-swizzle for a (64 x 1024) activation: element (m,k) at
// ((k>>5)*4 + (m>>4))*512 + ((m&15) + ((k>>3)&3)*16)*8 + (k&7).   [verified R1-R3]
__device__ __forceinline__ size_t aswz(int m, int k) {
    return ((size_t)((k >> 5) * 4 + (m >> 4)) * 64 + ((m & 15) + ((k >> 3) & 3) * 16)) * 8
           + (k & 7);
}

#define HOFF(p, l) (((size_t)(p) * 4 + (l)) * 65536)

// global -> LDS direct copy, 16B per lane. lds base must be wave-uniform;
// HW scatters lane i at ldsbase + i*16.  [guide §5, m97]
__device__ __forceinline__ void gl2lds16(const void* g, void* l) {
    __builtin_amdgcn_global_load_lds(
        (const __attribute__((address_space(1))) unsigned int*)g,
        (__attribute__((address_space(3))) unsigned int*)l, 16, 0, 0);
}

// ---------------------------------------------------------------------------
// prep_w (VERBATIM R3): fp32 W -> swizzled hi/lo bf16 stream.
// Wcat[l][bj][phase 16][tile 4][part 2][512]; tile = 2*kh + (kcl&1),
// phase = kcl>>1. Per-cell-per-block stream = 16 phases x 8 KB, sequential.
// ---------------------------------------------------------------------------
__global__ __launch_bounds__(256)
void prep_w(const float* __restrict__ Wih, const float* __restrict__ Whh,
            unsigned short* __restrict__ Wcat)
{
    int gid = blockIdx.x * 256 + threadIdx.x;      // (l, kc, nt, L)
    int L  = gid & 63;
    int nt = (gid >> 6) & 255;
    int kc = (gid >> 14) & 63;
    int l  = gid >> 20;                            // 0..3
    int np = nt * 16 + (L & 15);                   // n' in [0,4096)
    int g  = np & 3, j = np >> 2;
    int n  = g * 1024 + j;                         // original gate row
    int k0 = kc * 32 + (L >> 4) * 8;               // k in [0,2048)
    const float* src = (k0 < 1024)
        ? (Wih + ((size_t)l * 4096 + n) * 1024 + k0)
        : (Whh + ((size_t)l * 4096 + n) * 1024 + (k0 - 1024));
    float4 s0 = *(const float4*)(src);
    float4 s1 = *(const float4*)(src + 4);
    float sv[8] = {s0.x, s0.y, s0.z, s0.w, s1.x, s1.y, s1.z, s1.w};
    unsigned short hb[8], lb[8];
#pragma unroll
    for (int e = 0; e < 8; ++e) split_bf16(sv[e], hb[e], lb[e]);
    int kh = kc >> 5, kcl = kc & 31;
    int pph = kcl >> 1, tile = 2 * kh + (kcl & 1);
    size_t slotbase = ((size_t)(l * 256 + nt) * 16 + pph) * 4096;
    size_t dsthi = slotbase + (size_t)tile * 1024 + (size_t)L * 8;
    *(ushort4*)&Wcat[dsthi]       = make_ushort4(hb[0], hb[1], hb[2], hb[3]);
    *(ushort4*)&Wcat[dsthi + 4]   = make_ushort4(hb[4], hb[5], hb[6], hb[7]);
    *(ushort4*)&Wcat[dsthi + 512] = make_ushort4(lb[0], lb[1], lb[2], lb[3]);
    *(ushort4*)&Wcat[dsthi + 516] = make_ushort4(lb[4], lb[5], lb[6], lb[7]);
}

// ---------------------------------------------------------------------------
// prep_state (VERBATIM R3)
// ---------------------------------------------------------------------------
__global__ __launch_bounds__(256)
void prep_state(const float* __restrict__ x, const float* __restrict__ h0,
                unsigned short* __restrict__ Xhi, unsigned short* __restrict__ Xlo,
                unsigned short* __restrict__ Hhi, unsigned short* __restrict__ Hlo)
{
    int gid = blockIdx.x * 256 + threadIdx.x;
    if (gid >= 5 * 65536) return;
    int buf = gid >> 16;
    int e = gid & 65535;
    int b = e >> 10, jg = e & 1023;
    float v = (buf == 0) ? x[e] : h0[(size_t)(buf - 1) * 65536 + e];
    size_t idx = aswz(b, jg);
    unsigned short hh, hl; split_bf16(v, hh, hl);
    if (buf == 0) { Xhi[idx] = hh; Xlo[idx] = hl; }
    else {
        Hhi[(size_t)(buf - 1) * 65536 + idx] = hh;
        Hlo[(size_t)(buf - 1) * 65536 + idx] = hl;
    }
}

// ---------------------------------------------------------------------------
// lstm_fused R6: 512 cells, one persistent kernel.
// 256 blocks x 576 thr: waves 0..7 compute (4 M-quarters x 2 K-halves),
// wave 8 = barrier + epilogue wave (its ONLY vmem = epilogue stores, so the
// release-atomic's implicit vmcnt(0) never drains weight/A prefetches).
// Grid barrier: two-level tree (8 group counters -> global counter -> flag),
// all agent-scope; acquire/release chain preserved from the R3 protocol.
// B: global_load_lds into a 12-slot x 8KB LDS ring, issue distance 11.
// A: named 8-set register ring (constant indices only -> no scratch).
// Phase gate: s_waitcnt vmcnt(46) + s_barrier (counted, never drained).
// ---------------------------------------------------------------------------
#define WRAP12(x) ((x) >= 12 ? (x) - 12 : (x))

#define AISSUE(AV, pp) do {                                                   \
    const unsigned short* _ab = Ah + (size_t)(pp) * 4096 + alane;             \
    const unsigned short* _lb = Al + (size_t)(pp) * 4096 + alane;             \
    AV[0] = *(const bf16x8*)(_ab);                                            \
    AV[1] = *(const bf16x8*)(_lb);                                            \
    AV[2] = *(const bf16x8*)(_ab + 2048);                                     \
    AV[3] = *(const bf16x8*)(_lb + 2048);                                     \
} while (0)

#define PHASE(p, AV_C, AV_N) do {                                             \
    asm volatile("s_waitcnt vmcnt(46)\n\ts_barrier" ::: "memory");            \
    const int sp_ = WRAP12(cb + ((p) % 12));                                  \
    const unsigned short* bs_ = &Bls[sp_ * 4096 + kh * 2048];                 \
    bf16x8 bh0 = *(const bf16x8*)(bs_ +    0 + L * 8);                        \
    bf16x8 bl0 = *(const bf16x8*)(bs_ +  512 + L * 8);                        \
    bf16x8 bh1 = *(const bf16x8*)(bs_ + 1024 + L * 8);                        \
    bf16x8 bl1 = *(const bf16x8*)(bs_ + 1536 + L * 8);                        \
    acc0 = __builtin_amdgcn_mfma_f32_16x16x32_bf16(AV_C[0], bh0, acc0, 0, 0, 0); \
    acc1 = __builtin_amdgcn_mfma_f32_16x16x32_bf16(AV_C[1], bh0, acc1, 0, 0, 0); \
    acc2 = __builtin_amdgcn_mfma_f32_16x16x32_bf16(AV_C[0], bl0, acc2, 0, 0, 0); \
    acc0 = __builtin_amdgcn_mfma_f32_16x16x32_bf16(AV_C[2], bh1, acc0, 0, 0, 0); \
    acc1 = __builtin_amdgcn_mfma_f32_16x16x32_bf16(AV_C[3], bh1, acc1, 0, 0, 0); \
    acc2 = __builtin_amdgcn_mfma_f32_16x16x32_bf16(AV_C[2], bl1, acc2, 0, 0, 0); \
    AISSUE(AV_N, ((p) + 7) & 15);                                             \
    { const int si_ = WRAP12(cb + (((p) + 11) % 12));                         \
      const unsigned short* gsrc_ = ((p) < 5)                                 \
          ? (wsrc + ((p) + 11) * 4096) : (wnext + ((p) - 5) * 4096);          \
      gl2lds16(gsrc_ + (size_t)w * 512 + (size_t)L * 8,                       \
               &Bls[si_ * 4096 + w * 512]); }                                 \
} while (0)

__global__ __launch_bounds__(576, 2)
void lstm_fused(const unsigned short* __restrict__ Wcat,
                const unsigned short* __restrict__ Xhi, const unsigned short* __restrict__ Xlo,
                unsigned short* __restrict__ Hhi, unsigned short* __restrict__ Hlo,
                const float* __restrict__ c0,
                const float* __restrict__ bih, const float* __restrict__ bhh,
                float* __restrict__ out, unsigned* __restrict__ sync)
{
    __shared__ __align__(16) unsigned short Bls[12 * 4096];  // 96 KB, 12x8KB ring
    __shared__ __align__(16) float Gs[2560];                 // 8 tiles x 16 x 20 (pad)
    __shared__ __align__(16) float4 cLd[4][64];              // c state (block-private)
    __shared__ float bcs[64];                                // combined bias

    const int tid = threadIdx.x;
    const int L = tid & 63;
    const int w = tid >> 6;          // 0..8 (8 = barrier/epilogue wave)
    const int q = w & 3;             // M-quarter (compute waves)
    const int kh = w >> 2;           // K-half: 0 = input, 1 = recurrent
    const int bj = blockIdx.x;       // n'-tile
    const size_t alane = (size_t)q * 512 + (size_t)L * 8;

    // ---- one-time init: bias + c into LDS (wave8 only; wave8 consumes) ----
    if (tid >= 512) {
        int e = tid - 512;           // 0..63
        int li = e >> 4, i = e & 15;
        int jj = bj * 4 + (i >> 2), g = i & 3;
        bcs[e] = bih[li * 4096 + g * 1024 + jj] + bhh[li * 4096 + g * 1024 + jj];
#pragma unroll
        for (int li2 = 0; li2 < 4; ++li2) {
            const float* cs = c0 + (size_t)li2 * 65536 + (size_t)e * 1024 + bj * 4;
            cLd[li2][e] = make_float4(cs[0], cs[1], cs[2], cs[3]);
        }
    }

    bf16x8 av0[4], av1[4], av2[4], av3[4], av4[4], av5[4], av6[4], av7[4];
    const unsigned short *Ah = Xhi, *Al = Xlo, *wsrc = Wcat, *wnext = Wcat;
    int cb = 0;

    // ---- pre-loop prologue: cell 0 pointers, slots 0..10, A sets 0..6 ----
    if (tid < 512) {
        Ah = kh ? (Hhi + HOFF(0, 0)) : Xhi;
        Al = kh ? (Hlo + HOFF(0, 0)) : Xlo;
        wsrc  = Wcat + (size_t)bj * 65536;            // l=0
        wnext = Wcat + ((size_t)1 * 256 + bj) * 65536;
#pragma unroll
        for (int g = 0; g < 11; ++g)
            gl2lds16(wsrc + (size_t)g * 4096 + (size_t)w * 512 + (size_t)L * 8,
                     &Bls[g * 4096 + w * 512]);
        AISSUE(av0, 0); AISSUE(av1, 1); AISSUE(av2, 2); AISSUE(av3, 3);
        AISSUE(av4, 4); AISSUE(av5, 5); AISSUE(av6, 6);
        asm volatile("s_waitcnt vmcnt(0)" ::: "memory");
    }

#pragma unroll 1
    for (int u = 0; u < NT * NL; ++u) {
        const int t = u >> 2, l = u & 3;
        const int pr = t & 1, pw = pr ^ 1;

        // ---- grid barrier: two-level tree, executed by wave8 lane0 only.
        // Wave8's prior vmem = previous cell's epilogue stores, so the
        // release-RMW's vmcnt(0) drains exactly those (required) and never
        // the compute waves' prefetch queues.
        if (u) {
            if (tid == 512) {
                unsigned* cg = sync + ((unsigned)bj & 7u) * 16u;   // 64B apart
                unsigned old = __hip_atomic_fetch_add(cg, 1u, __ATOMIC_ACQ_REL,
                                                      __HIP_MEMORY_SCOPE_AGENT);
                bool done = false;
                if (old == 32u * (unsigned)u - 1u) {
                    unsigned o2 = __hip_atomic_fetch_add(sync + 128, 1u,
                                                         __ATOMIC_ACQ_REL,
                                                         __HIP_MEMORY_SCOPE_AGENT);
                    if (o2 == 8u * (unsigned)u - 1u) {
                        __hip_atomic_store(sync + 144, (unsigned)u, __ATOMIC_RELEASE,
                                           __HIP_MEMORY_SCOPE_AGENT);
                        done = true;
                    }
                }
                if (!done) {
                    while (__hip_atomic_load(sync + 144, __ATOMIC_RELAXED,
                                             __HIP_MEMORY_SCOPE_AGENT) < (unsigned)u)
                        __builtin_amdgcn_s_sleep(2);
                    (void)__hip_atomic_load(sync + 144, __ATOMIC_ACQUIRE,
                                            __HIP_MEMORY_SCOPE_AGENT);
                }
            }
            asm volatile("s_barrier" ::: "memory");
        }

        // ---- per-cell pointers (scalar only; harmless for wave8) ----
        {
            const unsigned short *AIh, *AIl;
            if (l == 0) {
                if (t == 0) { AIh = Xhi; AIl = Xlo; }
                else        { AIh = Hhi + HOFF(pr, 3); AIl = Hlo + HOFF(pr, 3); }
            } else          { AIh = Hhi + HOFF(pw, l - 1); AIl = Hlo + HOFF(pw, l - 1); }
            Ah = (kh == 1) ? (Hhi + HOFF(pr, l)) : AIh;
            Al = (kh == 1) ? (Hlo + HOFF(pr, l)) : AIl;
            wsrc  = Wcat + ((size_t)l * 256 + bj) * 65536;
            wnext = Wcat + ((size_t)((l + 1) & 3) * 256 + bj) * 65536;
        }

        if (tid < 512) {
            if (u) {
                AISSUE(av0, 0); AISSUE(av1, 1); AISSUE(av2, 2); AISSUE(av3, 3);
                AISSUE(av4, 4); AISSUE(av5, 5); AISSUE(av6, 6);
            }

            f32x4 acc0 = {0.f, 0.f, 0.f, 0.f};
            f32x4 acc1 = {0.f, 0.f, 0.f, 0.f};
            f32x4 acc2 = {0.f, 0.f, 0.f, 0.f};

            PHASE( 0, av0, av7);  PHASE( 1, av1, av0);  PHASE( 2, av2, av1);
            PHASE( 3, av3, av2);  PHASE( 4, av4, av3);  PHASE( 5, av5, av4);
            PHASE( 6, av6, av5);  PHASE( 7, av7, av6);  PHASE( 8, av0, av7);
            PHASE( 9, av1, av0);  PHASE(10, av2, av1);  PHASE(11, av3, av2);
            PHASE(12, av4, av3);  PHASE(13, av5, av4);  PHASE(14, av6, av5);
            PHASE(15, av7, av6);

            // ---- scatter partials: tile = kh*4+q; lane holds D[mq*4+r][nl] ----
            f32x4 avv = (acc0 + acc1) + acc2;
            const int mq = L >> 4, nl = L & 15;
            float* gw = &Gs[(kh * 4 + q) * 320 + nl];
#pragma unroll
            for (int r = 0; r < 4; ++r) gw[(mq * 4 + r) * 20] = avv[r];
        } else {
            // wave8: match the 16 per-phase barriers of the compute waves.
#pragma unroll
            for (int p = 0; p < 16; ++p)
                asm volatile("s_barrier" ::: "memory");
        }
        asm volatile("s_waitcnt lgkmcnt(0)\n\ts_barrier" ::: "memory");

        // ---- epilogue: wave8, one batch row per lane, 4 h-dims ----
        if (tid >= 512) {
            const int bl = tid - 512, qq = bl >> 4, ml = bl & 15;
            float4 cv = cLd[l][bl];
            float ca[4] = {cv.x, cv.y, cv.z, cv.w};
            float hv[4];
            ushort4 h_hi, h_lo;
#pragma unroll
            for (int jl = 0; jl < 4; ++jl) {
                const int base0 = (qq * 16 + ml) * 20 + jl * 4;
                float4 g0 = *(const float4*)&Gs[base0];
                float4 g1 = *(const float4*)&Gs[base0 + 1280];
                float4 bb = *(const float4*)&bcs[l * 16 + jl * 4];
                float gi = g0.x + g1.x + bb.x;
                float gf = g0.y + g1.y + bb.y;
                float gg = g0.z + g1.z + bb.z;
                float go = g0.w + g1.w + bb.w;
                float si = 1.f / (1.f + __expf(-gi));
                float sf = 1.f / (1.f + __expf(-gf));
                float so = 1.f / (1.f + __expf(-go));
                float tg = 1.f - 2.f / (__expf(2.f * gg) + 1.f);
                float cn = sf * ca[jl] + si * tg;
                ca[jl] = cn;
                float tc = 1.f - 2.f / (__expf(2.f * cn) + 1.f);
                hv[jl] = so * tc;
                unsigned short hh, hl; split_bf16(hv[jl], hh, hl);
                ((unsigned short*)&h_hi)[jl] = hh;
                ((unsigned short*)&h_lo)[jl] = hl;
            }
            cLd[l][bl] = make_float4(ca[0], ca[1], ca[2], ca[3]);
            size_t hidx = aswz(bl, bj * 4);
            union { ushort4 v; unsigned long long u; } ch, cl2;
            ch.v = h_hi; cl2.v = h_lo;
            __hip_atomic_store((unsigned long long*)(Hhi + HOFF(pw, l) + hidx), ch.u,
                               __ATOMIC_RELAXED, __HIP_MEMORY_SCOPE_AGENT);
            __hip_atomic_store((unsigned long long*)(Hlo + HOFF(pw, l) + hidx), cl2.u,
                               __ATOMIC_RELAXED, __HIP_MEMORY_SCOPE_AGENT);
            if (l == 3)
                *(float4*)&out[(size_t)bl * (NT * NH) + (size_t)t * NH + bj * 4]
                    = make_float4(hv[0], hv[1], hv[2], hv[3]);
        }

        cb += 4; if (cb >= 12) cb -= 12;
    }
}

// ---------------------------------------------------------------------------
extern "C" void kernel_launch(void* const* d_in, const int* in_sizes, int n_in,
                              void* d_out, int out_size, void* d_ws, size_t ws_size,
                              hipStream_t stream)
{
    const float* x   = (const float*)d_in[0];
    const float* h0  = (const float*)d_in[1];
    const float* c0  = (const float*)d_in[2];
    const float* Wih = (const float*)d_in[3];
    const float* Whh = (const float*)d_in[4];
    const float* bih = (const float*)d_in[5];
    const float* bhh = (const float*)d_in[6];
    float* out = (float*)d_out;

    char* ws = (char*)d_ws;
    size_t off = 0;
    auto alloc = [&](size_t bytes) -> char* {
        char* p = ws + off; off += (bytes + 255) & ~(size_t)255; return p;
    };
    unsigned short* Wcat = (unsigned short*)alloc((size_t)4 * 256 * 65536 * 2);  // 128 MiB
    unsigned short* Xhi  = (unsigned short*)alloc(65536 * 2);
    unsigned short* Xlo  = (unsigned short*)alloc(65536 * 2);
    unsigned short* Hhi  = (unsigned short*)alloc((size_t)2 * 4 * 65536 * 2);
    unsigned short* Hlo  = (unsigned short*)alloc((size_t)2 * 4 * 65536 * 2);
    unsigned*       sync = (unsigned*)alloc(1024);

    hipMemsetAsync(sync, 0, 1024, stream);
    prep_w<<<16384, 256, 0, stream>>>(Wih, Whh, Wcat);
    prep_state<<<1280, 256, 0, stream>>>(x, h0, Xhi, Xlo, Hhi, Hlo);

    void* kargs[] = { (void*)&Wcat, (void*)&Xhi, (void*)&Xlo, (void*)&Hhi, (void*)&Hlo,
                      (void*)&c0, (void*)&bih, (void*)&bhh, (void*)&out, (void*)&sync };
    hipLaunchCooperativeKernel((void*)lstm_fused, dim3(256), dim3(576), kargs, 0, stream);

    (void)in_sizes; (void)n_in; (void)out_size; (void)ws_size;
}

// Round 4
// 9168.619 us; speedup vs baseline: 1.1528x; 1.1528x over previous
//
#include <hip/hip_runtime.h>
#include <hip/hip_bf16.h>
#include <stdint.h>

// Problem constants (fixed by the reference): B=64, L=4, H=1024, T=128.
#define NB   64
#define NH   1024
#define NL   4
#define NT   128

using bf16x8 = __attribute__((ext_vector_type(8))) short;  // 8 bf16 in 4 VGPRs
using f32x4  = __attribute__((ext_vector_type(4))) float;

// Split fp32 v into hi+lo bf16 (RNE). v ~= hi + lo with residual ~2^-17 * |v|.
__device__ __forceinline__ void split_bf16(float v, unsigned short& hi, unsigned short& lo) {
    unsigned u = __float_as_uint(v);
    unsigned short h = (unsigned short)((u + 0x7FFFu + ((u >> 16) & 1u)) >> 16);
    float hf = __uint_as_float((unsigned)h << 16);
    float r  = v - hf;
    unsigned ur = __float_as_uint(r);
    unsigned short l = (unsigned short)((ur + 0x7FFFu + ((ur >> 16) & 1u)) >> 16);
    hi = h; lo = l;
}

// A-swizzle for a (64 x 1024) activation: element (m,k) at
// ((k>>5)*4 + (m>>4))*512 + ((m&15) + ((k>>3)&3)*16)*8 + (k&7).   [verified R1-R3]
__device__ __forceinline__ size_t aswz(int m, int k) {
    return ((size_t)((k >> 5) * 4 + (m >> 4)) * 64 + ((m & 15) + ((k >> 3) & 3) * 16)) * 8
           + (k & 7);
}

#define HOFF(p, l) (((size_t)(p) * 4 + (l)) * 65536)

// ---------------------------------------------------------------------------
// prep_w (VERBATIM R3): fp32 W -> swizzled hi/lo bf16 stream.
// Wcat[l][bj][phase 16][tile 4][part 2][512]; tile = 2*kh + (kcl&1),
// phase = kcl>>1. Per-cell-per-block stream = 16 phases x 8 KB, sequential.
// ---------------------------------------------------------------------------
__global__ __launch_bounds__(256)
void prep_w(const float* __restrict__ Wih, const float* __restrict__ Whh,
            unsigned short* __restrict__ Wcat)
{
    int gid = blockIdx.x * 256 + threadIdx.x;      // (l, kc, nt, L)
    int L  = gid & 63;
    int nt = (gid >> 6) & 255;
    int kc = (gid >> 14) & 63;
    int l  = gid >> 20;                            // 0..3
    int np = nt * 16 + (L & 15);                   // n' in [0,4096)
    int g  = np & 3, j = np >> 2;
    int n  = g * 1024 + j;                         // original gate row
    int k0 = kc * 32 + (L >> 4) * 8;               // k in [0,2048)
    const float* src = (k0 < 1024)
        ? (Wih + ((size_t)l * 4096 + n) * 1024 + k0)
        : (Whh + ((size_t)l * 4096 + n) * 1024 + (k0 - 1024));
    float4 s0 = *(const float4*)(src);
    float4 s1 = *(const float4*)(src + 4);
    float sv[8] = {s0.x, s0.y, s0.z, s0.w, s1.x, s1.y, s1.z, s1.w};
    unsigned short hb[8], lb[8];
#pragma unroll
    for (int e = 0; e < 8; ++e) split_bf16(sv[e], hb[e], lb[e]);
    int kh = kc >> 5, kcl = kc & 31;
    int pph = kcl >> 1, tile = 2 * kh + (kcl & 1);
    size_t slotbase = ((size_t)(l * 256 + nt) * 16 + pph) * 4096;
    size_t dsthi = slotbase + (size_t)tile * 1024 + (size_t)L * 8;
    *(ushort4*)&Wcat[dsthi]       = make_ushort4(hb[0], hb[1], hb[2], hb[3]);
    *(ushort4*)&Wcat[dsthi + 4]   = make_ushort4(hb[4], hb[5], hb[6], hb[7]);
    *(ushort4*)&Wcat[dsthi + 512] = make_ushort4(lb[0], lb[1], lb[2], lb[3]);
    *(ushort4*)&Wcat[dsthi + 516] = make_ushort4(lb[4], lb[5], lb[6], lb[7]);
}

// ---------------------------------------------------------------------------
// prep_state (VERBATIM R3)
// ---------------------------------------------------------------------------
__global__ __launch_bounds__(256)
void prep_state(const float* __restrict__ x, const float* __restrict__ h0,
                unsigned short* __restrict__ Xhi, unsigned short* __restrict__ Xlo,
                unsigned short* __restrict__ Hhi, unsigned short* __restrict__ Hlo)
{
    int gid = blockIdx.x * 256 + threadIdx.x;
    if (gid >= 5 * 65536) return;
    int buf = gid >> 16;
    int e = gid & 65535;
    int b = e >> 10, jg = e & 1023;
    float v = (buf == 0) ? x[e] : h0[(size_t)(buf - 1) * 65536 + e];
    size_t idx = aswz(b, jg);
    unsigned short hh, hl; split_bf16(v, hh, hl);
    if (buf == 0) { Xhi[idx] = hh; Xlo[idx] = hl; }
    else {
        Hhi[(size_t)(buf - 1) * 65536 + idx] = hh;
        Hlo[(size_t)(buf - 1) * 65536 + idx] = hl;
    }
}

// ---------------------------------------------------------------------------
// lstm_fused R7: 512 cells, persistent kernel, 256 blocks x 512 thr.
// STRUCTURAL CHANGE vs R3: the LDS B-ring is GONE. The R3 LDS layout was a
// pure pass-through (lane L read byte L*16 of piece p' == the gl2lds lane
// scatter of the global source), so each wave now loads its own B fragments
// straight from Wcat into a 4-set register ring (addresses bit-identical to
// the verified LDS-read/scatter composition):
//   frag f of phase ph for (kh, lane L) = wsrc + ph*4096 + kh*2048 + f*512 + L*8.
// This removes ALL intra-cell barriers (16 per cell, 8192 block-wide syncs
// total) — the per-phase vmcnt(14)+s_barrier lockstep forced every wave to
// stall at max-of-8-waves each phase with zero cross-wave latency hiding.
// Waves now run the 16 phases asynchronously; compiler emits precise
// per-register waits. Cost: B not deduped across the 4 q-waves (~4x B
// requests, mostly L1/L2 hits). A-issue guarded (p<13) to kill R3's stale
// wrapped A-loads (~96 KB/cell waste).
// Grid barrier, scatter, epilogue: verbatim R3.
// ---------------------------------------------------------------------------

#define AISSUE(AV, pp) do {                                                   \
    const unsigned short* _ab = Ah + (size_t)(pp) * 4096 + alane;             \
    const unsigned short* _lb = Al + (size_t)(pp) * 4096 + alane;             \
    AV[0] = *(const bf16x8*)(_ab);                                            \
    AV[1] = *(const bf16x8*)(_lb);                                            \
    AV[2] = *(const bf16x8*)(_ab + 2048);                                     \
    AV[3] = *(const bf16x8*)(_lb + 2048);                                     \
} while (0)

#define BISSUE(BV, pp, stream) do {                                           \
    const unsigned short* _bb = (stream) + (size_t)(pp) * 4096 + blane;       \
    BV[0] = *(const bf16x8*)(_bb);            /* bh0 */                       \
    BV[1] = *(const bf16x8*)(_bb + 512);      /* bl0 */                       \
    BV[2] = *(const bf16x8*)(_bb + 1024);     /* bh1 */                       \
    BV[3] = *(const bf16x8*)(_bb + 1536);     /* bl1 */                       \
} while (0)

#define PHASE(p, AV_C, BV_C, AV_N, BV_N) do {                                 \
    acc0 = __builtin_amdgcn_mfma_f32_16x16x32_bf16(AV_C[0], BV_C[0], acc0, 0, 0, 0); \
    acc1 = __builtin_amdgcn_mfma_f32_16x16x32_bf16(AV_C[1], BV_C[0], acc1, 0, 0, 0); \
    acc2 = __builtin_amdgcn_mfma_f32_16x16x32_bf16(AV_C[0], BV_C[1], acc2, 0, 0, 0); \
    acc0 = __builtin_amdgcn_mfma_f32_16x16x32_bf16(AV_C[2], BV_C[2], acc0, 0, 0, 0); \
    acc1 = __builtin_amdgcn_mfma_f32_16x16x32_bf16(AV_C[3], BV_C[2], acc1, 0, 0, 0); \
    acc2 = __builtin_amdgcn_mfma_f32_16x16x32_bf16(AV_C[2], BV_C[3], acc2, 0, 0, 0); \
    if ((p) < 13) { AISSUE(AV_N, (p) + 3); BISSUE(BV_N, (p) + 3, wsrc); }     \
    else          { BISSUE(BV_N, (p) - 13, wnext); }                          \
} while (0)

__global__ __launch_bounds__(512, 2)
void lstm_fused(const unsigned short* __restrict__ Wcat,
                const unsigned short* __restrict__ Xhi, const unsigned short* __restrict__ Xlo,
                unsigned short* __restrict__ Hhi, unsigned short* __restrict__ Hlo,
                const float* __restrict__ c0,
                const float* __restrict__ bih, const float* __restrict__ bhh,
                float* __restrict__ out, unsigned* __restrict__ sync)
{
    __shared__ __align__(16) float Gs[2560];                 // 8 tiles x 16 x 20 (pad)
    __shared__ __align__(16) float4 cLd[4][64];              // c state (block-private)
    __shared__ float bcs[64];                                // combined bias

    const int tid = threadIdx.x;
    const int L = tid & 63;
    const int w = tid >> 6;          // 0..7
    const int q = w & 3;             // M-quarter
    const int kh = w >> 2;           // K-half: 0 = input, 1 = recurrent
    const int bj = blockIdx.x;       // n'-tile
    const size_t alane = (size_t)q * 512 + (size_t)L * 8;
    const size_t blane = (size_t)kh * 2048 + (size_t)L * 8;
    unsigned* cnt  = sync;
    unsigned* flag = sync + 32;

    // ---- one-time init: bias + c into LDS (wave0 only; wave0 consumes) ----
    if (tid < 64) {
        int li = tid >> 4, i = tid & 15;
        int jj = bj * 4 + (i >> 2), g = i & 3;
        bcs[tid] = bih[li * 4096 + g * 1024 + jj] + bhh[li * 4096 + g * 1024 + jj];
#pragma unroll
        for (int li2 = 0; li2 < 4; ++li2) {
            const float* cs = c0 + (size_t)li2 * 65536 + (size_t)tid * 1024 + bj * 4;
            cLd[li2][tid] = make_float4(cs[0], cs[1], cs[2], cs[3]);
        }
    }

    bf16x8 av0[4], av1[4], av2[4], av3[4];
    bf16x8 bv0[4], bv1[4], bv2[4], bv3[4];
    const unsigned short *Ah, *Al, *wsrc, *wnext;

    // ---- pre-loop prologue: cell 0 pointers, A sets 0..2, B sets 0..2 ----
    {
        Ah = kh ? (Hhi + HOFF(0, 0)) : Xhi;
        Al = kh ? (Hlo + HOFF(0, 0)) : Xlo;
        wsrc  = Wcat + (size_t)bj * 65536;            // l=0
        wnext = Wcat + ((size_t)1 * 256 + bj) * 65536;
        BISSUE(bv0, 0, wsrc); BISSUE(bv1, 1, wsrc); BISSUE(bv2, 2, wsrc);
        AISSUE(av0, 0); AISSUE(av1, 1); AISSUE(av2, 2);
    }

#pragma unroll 1
    for (int u = 0; u < NT * NL; ++u) {
        const int t = u >> 2, l = u & 3;
        const int pr = t & 1, pw = pr ^ 1;

        // ---- grid barrier (R3-verified protocol) ----
        if (u) {
            if (tid == 0) {
                unsigned old = __hip_atomic_fetch_add(cnt, 1u, __ATOMIC_ACQ_REL,
                                                      __HIP_MEMORY_SCOPE_AGENT);
                if (old == 256u * (unsigned)u - 1u) {
                    __hip_atomic_store(flag, (unsigned)u, __ATOMIC_RELEASE,
                                       __HIP_MEMORY_SCOPE_AGENT);
                } else {
                    while (__hip_atomic_load(flag, __ATOMIC_RELAXED,
                                             __HIP_MEMORY_SCOPE_AGENT) < (unsigned)u)
                        __builtin_amdgcn_s_sleep(2);
                    (void)__hip_atomic_load(flag, __ATOMIC_ACQUIRE,
                                            __HIP_MEMORY_SCOPE_AGENT);
                }
            }
            asm volatile("s_barrier" ::: "memory");
        }

        // ---- per-cell pointers ----
        {
            const unsigned short *AIh, *AIl;
            if (l == 0) {
                if (t == 0) { AIh = Xhi; AIl = Xlo; }
                else        { AIh = Hhi + HOFF(pr, 3); AIl = Hlo + HOFF(pr, 3); }
            } else          { AIh = Hhi + HOFF(pw, l - 1); AIl = Hlo + HOFF(pw, l - 1); }
            Ah = kh ? (Hhi + HOFF(pr, l)) : AIh;
            Al = kh ? (Hlo + HOFF(pr, l)) : AIl;
            wsrc  = Wcat + ((size_t)l * 256 + bj) * 65536;
            wnext = Wcat + ((size_t)((l + 1) & 3) * 256 + bj) * 65536;
        }
        // A sets 0..2 for this cell (h was just produced; B sets 0..2 were
        // prefetched from wnext during the previous cell's phases 13..15).
        if (u) { AISSUE(av0, 0); AISSUE(av1, 1); AISSUE(av2, 2); }

        f32x4 acc0 = {0.f, 0.f, 0.f, 0.f};
        f32x4 acc1 = {0.f, 0.f, 0.f, 0.f};
        f32x4 acc2 = {0.f, 0.f, 0.f, 0.f};

        PHASE( 0, av0, bv0, av3, bv3);  PHASE( 1, av1, bv1, av0, bv0);
        PHASE( 2, av2, bv2, av1, bv1);  PHASE( 3, av3, bv3, av2, bv2);
        PHASE( 4, av0, bv0, av3, bv3);  PHASE( 5, av1, bv1, av0, bv0);
        PHASE( 6, av2, bv2, av1, bv1);  PHASE( 7, av3, bv3, av2, bv2);
        PHASE( 8, av0, bv0, av3, bv3);  PHASE( 9, av1, bv1, av0, bv0);
        PHASE(10, av2, bv2, av1, bv1);  PHASE(11, av3, bv3, av2, bv2);
        PHASE(12, av0, bv0, av3, bv3);  PHASE(13, av1, bv1, av0, bv0);
        PHASE(14, av2, bv2, av1, bv1);  PHASE(15, av3, bv3, av2, bv2);

        // ---- scatter partials: tile = kh*4+q; lane holds D[mq*4+r][nl] ----
        {
            f32x4 avv = (acc0 + acc1) + acc2;
            const int mq = L >> 4, nl = L & 15;
            float* gw = &Gs[(kh * 4 + q) * 320 + nl];
#pragma unroll
            for (int r = 0; r < 4; ++r) gw[(mq * 4 + r) * 20] = avv[r];
        }
        asm volatile("s_waitcnt lgkmcnt(0)\n\ts_barrier" ::: "memory");

        // ---- epilogue: wave0, one batch row each, 4 h-dims (R3-verified) ----
        if (tid < 64) {
            const int bl = tid, qq = bl >> 4, ml = bl & 15;
            float4 cv = cLd[l][bl];
            float ca[4] = {cv.x, cv.y, cv.z, cv.w};
            float hv[4];
            ushort4 h_hi, h_lo;
#pragma unroll
            for (int jl = 0; jl < 4; ++jl) {
                const int base0 = (qq * 16 + ml) * 20 + jl * 4;
                float4 g0 = *(const float4*)&Gs[base0];
                float4 g1 = *(const float4*)&Gs[base0 + 1280];
                float4 bb = *(const float4*)&bcs[l * 16 + jl * 4];
                float gi = g0.x + g1.x + bb.x;
                float gf = g0.y + g1.y + bb.y;
                float gg = g0.z + g1.z + bb.z;
                float go = g0.w + g1.w + bb.w;
                float si = 1.f / (1.f + __expf(-gi));
                float sf = 1.f / (1.f + __expf(-gf));
                float so = 1.f / (1.f + __expf(-go));
                float tg = 1.f - 2.f / (__expf(2.f * gg) + 1.f);
                float cn = sf * ca[jl] + si * tg;
                ca[jl] = cn;
                float tc = 1.f - 2.f / (__expf(2.f * cn) + 1.f);
                hv[jl] = so * tc;
                unsigned short hh, hl; split_bf16(hv[jl], hh, hl);
                ((unsigned short*)&h_hi)[jl] = hh;
                ((unsigned short*)&h_lo)[jl] = hl;
            }
            cLd[l][bl] = make_float4(ca[0], ca[1], ca[2], ca[3]);
            size_t hidx = aswz(bl, bj * 4);
            union { ushort4 v; unsigned long long u; } ch, cl2;
            ch.v = h_hi; cl2.v = h_lo;
            __hip_atomic_store((unsigned long long*)(Hhi + HOFF(pw, l) + hidx), ch.u,
                               __ATOMIC_RELAXED, __HIP_MEMORY_SCOPE_AGENT);
            __hip_atomic_store((unsigned long long*)(Hlo + HOFF(pw, l) + hidx), cl2.u,
                               __ATOMIC_RELAXED, __HIP_MEMORY_SCOPE_AGENT);
            if (l == 3)
                *(float4*)&out[(size_t)bl * (NT * NH) + (size_t)t * NH + bj * 4]
                    = make_float4(hv[0], hv[1], hv[2], hv[3]);
        }
    }
}

// ---------------------------------------------------------------------------
extern "C" void kernel_launch(void* const* d_in, const int* in_sizes, int n_in,
                              void* d_out, int out_size, void* d_ws, size_t ws_size,
                              hipStream_t stream)
{
    const float* x   = (const float*)d_in[0];
    const float* h0  = (const float*)d_in[1];
    const float* c0  = (const float*)d_in[2];
    const float* Wih = (const float*)d_in[3];
    const float* Whh = (const float*)d_in[4];
    const float* bih = (const float*)d_in[5];
    const float* bhh = (const float*)d_in[6];
    float* out = (float*)d_out;

    char* ws = (char*)d_ws;
    size_t off = 0;
    auto alloc = [&](size_t bytes) -> char* {
        char* p = ws + off; off += (bytes + 255) & ~(size_t)255; return p;
    };
    unsigned short* Wcat = (unsigned short*)alloc((size_t)4 * 256 * 65536 * 2);  // 128 MiB
    unsigned short* Xhi  = (unsigned short*)alloc(65536 * 2);
    unsigned short* Xlo  = (unsigned short*)alloc(65536 * 2);
    unsigned short* Hhi  = (unsigned short*)alloc((size_t)2 * 4 * 65536 * 2);
    unsigned short* Hlo  = (unsigned short*)alloc((size_t)2 * 4 * 65536 * 2);
    unsigned*       sync = (unsigned*)alloc(256);

    hipMemsetAsync(sync, 0, 256, stream);
    prep_w<<<16384, 256, 0, stream>>>(Wih, Whh, Wcat);
    prep_state<<<1280, 256, 0, stream>>>(x, h0, Xhi, Xlo, Hhi, Hlo);

    void* kargs[] = { (void*)&Wcat, (void*)&Xhi, (void*)&Xlo, (void*)&Hhi, (void*)&Hlo,
                      (void*)&c0, (void*)&bih, (void*)&bhh, (void*)&out, (void*)&sync };
    hipLaunchCooperativeKernel((void*)lstm_fused, dim3(256), dim3(512), kargs, 0, stream);

    (void)in_sizes; (void)n_in; (void)out_size; (void)ws_size;
}

// Round 5
// 8905.085 us; speedup vs baseline: 1.1869x; 1.0296x over previous
//
#include <hip/hip_runtime.h>
#include <hip/hip_bf16.h>
#include <stdint.h>

// Problem constants (fixed by the reference): B=64, L=4, H=1024, T=128.
#define NB   64
#define NH   1024
#define NL   4
#define NT   128

using bf16x8 = __attribute__((ext_vector_type(8))) short;  // 8 bf16 in 4 VGPRs
using f32x4  = __attribute__((ext_vector_type(4))) float;

// Split fp32 v into hi+lo bf16 (RNE). v ~= hi + lo with residual ~2^-17 * |v|.
__device__ __forceinline__ void split_bf16(float v, unsigned short& hi, unsigned short& lo) {
    unsigned u = __float_as_uint(v);
    unsigned short h = (unsigned short)((u + 0x7FFFu + ((u >> 16) & 1u)) >> 16);
    float hf = __uint_as_float((unsigned)h << 16);
    float r  = v - hf;
    unsigned ur = __float_as_uint(r);
    unsigned short l = (unsigned short)((ur + 0x7FFFu + ((ur >> 16) & 1u)) >> 16);
    hi = h; lo = l;
}

// A-swizzle for a (64 x 1024) activation: element (m,k) at
// ((k>>5)*4 + (m>>4))*512 + ((m&15) + ((k>>3)&3)*16)*8 + (k&7).   [verified R1-R3]
__device__ __forceinline__ size_t aswz(int m, int k) {
    return ((size_t)((k >> 5) * 4 + (m >> 4)) * 64 + ((m & 15) + ((k >> 3) & 3) * 16)) * 8
           + (k & 7);
}

#define HOFF(p, l) (((size_t)(p) * 4 + (l)) * 65536)

// ---------------------------------------------------------------------------
// prep_w (VERBATIM R3): fp32 W -> swizzled hi/lo bf16 stream.
// Wcat[l][bj][phase 16][tile 4][part 2][512]; tile = 2*kh + (kcl&1),
// phase = kcl>>1. Per-cell-per-block stream = 16 phases x 8 KB, sequential.
// ---------------------------------------------------------------------------
__global__ __launch_bounds__(256)
void prep_w(const float* __restrict__ Wih, const float* __restrict__ Whh,
            unsigned short* __restrict__ Wcat)
{
    int gid = blockIdx.x * 256 + threadIdx.x;      // (l, kc, nt, L)
    int L  = gid & 63;
    int nt = (gid >> 6) & 255;
    int kc = (gid >> 14) & 63;
    int l  = gid >> 20;                            // 0..3
    int np = nt * 16 + (L & 15);                   // n' in [0,4096)
    int g  = np & 3, j = np >> 2;
    int n  = g * 1024 + j;                         // original gate row
    int k0 = kc * 32 + (L >> 4) * 8;               // k in [0,2048)
    const float* src = (k0 < 1024)
        ? (Wih + ((size_t)l * 4096 + n) * 1024 + k0)
        : (Whh + ((size_t)l * 4096 + n) * 1024 + (k0 - 1024));
    float4 s0 = *(const float4*)(src);
    float4 s1 = *(const float4*)(src + 4);
    float sv[8] = {s0.x, s0.y, s0.z, s0.w, s1.x, s1.y, s1.z, s1.w};
    unsigned short hb[8], lb[8];
#pragma unroll
    for (int e = 0; e < 8; ++e) split_bf16(sv[e], hb[e], lb[e]);
    int kh = kc >> 5, kcl = kc & 31;
    int pph = kcl >> 1, tile = 2 * kh + (kcl & 1);
    size_t slotbase = ((size_t)(l * 256 + nt) * 16 + pph) * 4096;
    size_t dsthi = slotbase + (size_t)tile * 1024 + (size_t)L * 8;
    *(ushort4*)&Wcat[dsthi]       = make_ushort4(hb[0], hb[1], hb[2], hb[3]);
    *(ushort4*)&Wcat[dsthi + 4]   = make_ushort4(hb[4], hb[5], hb[6], hb[7]);
    *(ushort4*)&Wcat[dsthi + 512] = make_ushort4(lb[0], lb[1], lb[2], lb[3]);
    *(ushort4*)&Wcat[dsthi + 516] = make_ushort4(lb[4], lb[5], lb[6], lb[7]);
}

// ---------------------------------------------------------------------------
// prep_state (VERBATIM R3)
// ---------------------------------------------------------------------------
__global__ __launch_bounds__(256)
void prep_state(const float* __restrict__ x, const float* __restrict__ h0,
                unsigned short* __restrict__ Xhi, unsigned short* __restrict__ Xlo,
                unsigned short* __restrict__ Hhi, unsigned short* __restrict__ Hlo)
{
    int gid = blockIdx.x * 256 + threadIdx.x;
    if (gid >= 5 * 65536) return;
    int buf = gid >> 16;
    int e = gid & 65535;
    int b = e >> 10, jg = e & 1023;
    float v = (buf == 0) ? x[e] : h0[(size_t)(buf - 1) * 65536 + e];
    size_t idx = aswz(b, jg);
    unsigned short hh, hl; split_bf16(v, hh, hl);
    if (buf == 0) { Xhi[idx] = hh; Xlo[idx] = hl; }
    else {
        Hhi[(size_t)(buf - 1) * 65536 + idx] = hh;
        Hlo[(size_t)(buf - 1) * 65536 + idx] = hl;
    }
}

// ---------------------------------------------------------------------------
// lstm_fused R8: 512 cells, persistent kernel, 256 blocks x 512 thr.
// R7 structure (no LDS B-ring, no intra-cell barriers) + ENFORCED pipeline
// depth. R7's VGPR_Count=80 proved the compiler collapsed the named rings
// (sank each load to just before its use -> effective depth ~1 phase ->
// every phase serially exposed to L2/HBM latency). Now:
//   - __builtin_amdgcn_sched_barrier(0) at the END of every phase pins each
//     phase's loads to its phase (no sinking); compiler still schedules
//     freely within a phase and emits precise counted vmcnt waits.
//   - A: 4-deep ring (burst sets 0..3 at cell start; phase p<=11 reloads
//     the just-consumed name with set p+4).
//   - B: 6-deep ring over 8 names (phase p consumes bw[p&7]; issues set
//     p+6 (wsrc) for p<=9, set p-10 (wnext) for p>=10 into bw[(p+6)&7]).
// Expected VGPR ~190-220 (the signature that the depth is now real).
// Grid barrier, scatter, epilogue: verbatim R3/R7.
// ---------------------------------------------------------------------------

#define AISSUE(AV, pp) do {                                                   \
    const unsigned short* _ab = Ah + (size_t)(pp) * 4096 + alane;             \
    const unsigned short* _lb = Al + (size_t)(pp) * 4096 + alane;             \
    AV[0] = *(const bf16x8*)(_ab);                                            \
    AV[1] = *(const bf16x8*)(_lb);                                            \
    AV[2] = *(const bf16x8*)(_ab + 2048);                                     \
    AV[3] = *(const bf16x8*)(_lb + 2048);                                     \
} while (0)

#define BISSUE(BV, pp, stream) do {                                           \
    const unsigned short* _bb = (stream) + (size_t)(pp) * 4096 + blane;       \
    BV[0] = *(const bf16x8*)(_bb);            /* bh0 */                       \
    BV[1] = *(const bf16x8*)(_bb + 512);      /* bl0 */                       \
    BV[2] = *(const bf16x8*)(_bb + 1024);     /* bh1 */                       \
    BV[3] = *(const bf16x8*)(_bb + 1536);     /* bl1 */                       \
} while (0)

// Phase p: consume A name AC (= av[p&3]) and B name BC (= bw[p&7]);
// reload AC with A set p+4 (p<=11); load B into BN (= bw[(p+6)&7]).
#define PHASE(p, AC, BC, BN) do {                                             \
    acc0 = __builtin_amdgcn_mfma_f32_16x16x32_bf16(AC[0], BC[0], acc0, 0, 0, 0); \
    acc1 = __builtin_amdgcn_mfma_f32_16x16x32_bf16(AC[1], BC[0], acc1, 0, 0, 0); \
    acc2 = __builtin_amdgcn_mfma_f32_16x16x32_bf16(AC[0], BC[1], acc2, 0, 0, 0); \
    acc0 = __builtin_amdgcn_mfma_f32_16x16x32_bf16(AC[2], BC[2], acc0, 0, 0, 0); \
    acc1 = __builtin_amdgcn_mfma_f32_16x16x32_bf16(AC[3], BC[2], acc1, 0, 0, 0); \
    acc2 = __builtin_amdgcn_mfma_f32_16x16x32_bf16(AC[2], BC[3], acc2, 0, 0, 0); \
    if ((p) <= 11) AISSUE(AC, (p) + 4);                                       \
    if ((p) <= 9)  BISSUE(BN, (p) + 6, wsrc);                                 \
    else           BISSUE(BN, (p) - 10, wnext);                               \
    __builtin_amdgcn_sched_barrier(0);                                        \
} while (0)

__global__ __launch_bounds__(512, 2)
void lstm_fused(const unsigned short* __restrict__ Wcat,
                const unsigned short* __restrict__ Xhi, const unsigned short* __restrict__ Xlo,
                unsigned short* __restrict__ Hhi, unsigned short* __restrict__ Hlo,
                const float* __restrict__ c0,
                const float* __restrict__ bih, const float* __restrict__ bhh,
                float* __restrict__ out, unsigned* __restrict__ sync)
{
    __shared__ __align__(16) float Gs[2560];                 // 8 tiles x 16 x 20 (pad)
    __shared__ __align__(16) float4 cLd[4][64];              // c state (block-private)
    __shared__ float bcs[64];                                // combined bias

    const int tid = threadIdx.x;
    const int L = tid & 63;
    const int w = tid >> 6;          // 0..7
    const int q = w & 3;             // M-quarter
    const int kh = w >> 2;           // K-half: 0 = input, 1 = recurrent
    const int bj = blockIdx.x;       // n'-tile
    const size_t alane = (size_t)q * 512 + (size_t)L * 8;
    const size_t blane = (size_t)kh * 2048 + (size_t)L * 8;
    unsigned* cnt  = sync;
    unsigned* flag = sync + 32;

    // ---- one-time init: bias + c into LDS (wave0 only; wave0 consumes) ----
    if (tid < 64) {
        int li = tid >> 4, i = tid & 15;
        int jj = bj * 4 + (i >> 2), g = i & 3;
        bcs[tid] = bih[li * 4096 + g * 1024 + jj] + bhh[li * 4096 + g * 1024 + jj];
#pragma unroll
        for (int li2 = 0; li2 < 4; ++li2) {
            const float* cs = c0 + (size_t)li2 * 65536 + (size_t)tid * 1024 + bj * 4;
            cLd[li2][tid] = make_float4(cs[0], cs[1], cs[2], cs[3]);
        }
    }

    bf16x8 av0[4], av1[4], av2[4], av3[4];
    bf16x8 bw0[4], bw1[4], bw2[4], bw3[4], bw4[4], bw5[4], bw6[4], bw7[4];
    const unsigned short *Ah, *Al, *wsrc, *wnext;

    // ---- pre-loop prologue: B sets 0..5 of cell 0 into bw0..bw5 ----
    {
        wsrc  = Wcat + (size_t)bj * 65536;            // l=0
        wnext = Wcat + ((size_t)1 * 256 + bj) * 65536;
        BISSUE(bw0, 0, wsrc); BISSUE(bw1, 1, wsrc); BISSUE(bw2, 2, wsrc);
        BISSUE(bw3, 3, wsrc); BISSUE(bw4, 4, wsrc); BISSUE(bw5, 5, wsrc);
        __builtin_amdgcn_sched_barrier(0);
    }

#pragma unroll 1
    for (int u = 0; u < NT * NL; ++u) {
        const int t = u >> 2, l = u & 3;
        const int pr = t & 1, pw = pr ^ 1;

        // ---- grid barrier (R3-verified protocol) ----
        if (u) {
            if (tid == 0) {
                unsigned old = __hip_atomic_fetch_add(cnt, 1u, __ATOMIC_ACQ_REL,
                                                      __HIP_MEMORY_SCOPE_AGENT);
                if (old == 256u * (unsigned)u - 1u) {
                    __hip_atomic_store(flag, (unsigned)u, __ATOMIC_RELEASE,
                                       __HIP_MEMORY_SCOPE_AGENT);
                } else {
                    while (__hip_atomic_load(flag, __ATOMIC_RELAXED,
                                             __HIP_MEMORY_SCOPE_AGENT) < (unsigned)u)
                        __builtin_amdgcn_s_sleep(2);
                    (void)__hip_atomic_load(flag, __ATOMIC_ACQUIRE,
                                            __HIP_MEMORY_SCOPE_AGENT);
                }
            }
            asm volatile("s_barrier" ::: "memory");
        }

        // ---- per-cell pointers ----
        {
            const unsigned short *AIh, *AIl;
            if (l == 0) {
                if (t == 0) { AIh = Xhi; AIl = Xlo; }
                else        { AIh = Hhi + HOFF(pr, 3); AIl = Hlo + HOFF(pr, 3); }
            } else          { AIh = Hhi + HOFF(pw, l - 1); AIl = Hlo + HOFF(pw, l - 1); }
            Ah = kh ? (Hhi + HOFF(pr, l)) : AIh;
            Al = kh ? (Hlo + HOFF(pr, l)) : AIl;
            wsrc  = Wcat + ((size_t)l * 256 + bj) * 65536;
            wnext = Wcat + ((size_t)((l + 1) & 3) * 256 + bj) * 65536;
        }

        // ---- A burst: sets 0..3 of this cell (h just became visible) ----
        AISSUE(av0, 0); AISSUE(av1, 1); AISSUE(av2, 2); AISSUE(av3, 3);
        __builtin_amdgcn_sched_barrier(0);

        f32x4 acc0 = {0.f, 0.f, 0.f, 0.f};
        f32x4 acc1 = {0.f, 0.f, 0.f, 0.f};
        f32x4 acc2 = {0.f, 0.f, 0.f, 0.f};

        PHASE( 0, av0, bw0, bw6);  PHASE( 1, av1, bw1, bw7);
        PHASE( 2, av2, bw2, bw0);  PHASE( 3, av3, bw3, bw1);
        PHASE( 4, av0, bw4, bw2);  PHASE( 5, av1, bw5, bw3);
        PHASE( 6, av2, bw6, bw4);  PHASE( 7, av3, bw7, bw5);
        PHASE( 8, av0, bw0, bw6);  PHASE( 9, av1, bw1, bw7);
        PHASE(10, av2, bw2, bw0);  PHASE(11, av3, bw3, bw1);
        PHASE(12, av0, bw4, bw2);  PHASE(13, av1, bw5, bw3);
        PHASE(14, av2, bw6, bw4);  PHASE(15, av3, bw7, bw5);

        // ---- scatter partials: tile = kh*4+q; lane holds D[mq*4+r][nl] ----
        {
            f32x4 avv = (acc0 + acc1) + acc2;
            const int mq = L >> 4, nl = L & 15;
            float* gw = &Gs[(kh * 4 + q) * 320 + nl];
#pragma unroll
            for (int r = 0; r < 4; ++r) gw[(mq * 4 + r) * 20] = avv[r];
        }
        asm volatile("s_waitcnt lgkmcnt(0)\n\ts_barrier" ::: "memory");

        // ---- epilogue: wave0, one batch row each, 4 h-dims (R3-verified) ----
        if (tid < 64) {
            const int bl = tid, qq = bl >> 4, ml = bl & 15;
            float4 cv = cLd[l][bl];
            float ca[4] = {cv.x, cv.y, cv.z, cv.w};
            float hv[4];
            ushort4 h_hi, h_lo;
#pragma unroll
            for (int jl = 0; jl < 4; ++jl) {
                const int base0 = (qq * 16 + ml) * 20 + jl * 4;
                float4 g0 = *(const float4*)&Gs[base0];
                float4 g1 = *(const float4*)&Gs[base0 + 1280];
                float4 bb = *(const float4*)&bcs[l * 16 + jl * 4];
                float gi = g0.x + g1.x + bb.x;
                float gf = g0.y + g1.y + bb.y;
                float gg = g0.z + g1.z + bb.z;
                float go = g0.w + g1.w + bb.w;
                float si = 1.f / (1.f + __expf(-gi));
                float sf = 1.f / (1.f + __expf(-gf));
                float so = 1.f / (1.f + __expf(-go));
                float tg = 1.f - 2.f / (__expf(2.f * gg) + 1.f);
                float cn = sf * ca[jl] + si * tg;
                ca[jl] = cn;
                float tc = 1.f - 2.f / (__expf(2.f * cn) + 1.f);
                hv[jl] = so * tc;
                unsigned short hh, hl; split_bf16(hv[jl], hh, hl);
                ((unsigned short*)&h_hi)[jl] = hh;
                ((unsigned short*)&h_lo)[jl] = hl;
            }
            cLd[l][bl] = make_float4(ca[0], ca[1], ca[2], ca[3]);
            size_t hidx = aswz(bl, bj * 4);
            union { ushort4 v; unsigned long long u; } ch, cl2;
            ch.v = h_hi; cl2.v = h_lo;
            __hip_atomic_store((unsigned long long*)(Hhi + HOFF(pw, l) + hidx), ch.u,
                               __ATOMIC_RELAXED, __HIP_MEMORY_SCOPE_AGENT);
            __hip_atomic_store((unsigned long long*)(Hlo + HOFF(pw, l) + hidx), cl2.u,
                               __ATOMIC_RELAXED, __HIP_MEMORY_SCOPE_AGENT);
            if (l == 3)
                *(float4*)&out[(size_t)bl * (NT * NH) + (size_t)t * NH + bj * 4]
                    = make_float4(hv[0], hv[1], hv[2], hv[3]);
        }
    }
}

// ---------------------------------------------------------------------------
extern "C" void kernel_launch(void* const* d_in, const int* in_sizes, int n_in,
                              void* d_out, int out_size, void* d_ws, size_t ws_size,
                              hipStream_t stream)
{
    const float* x   = (const float*)d_in[0];
    const float* h0  = (const float*)d_in[1];
    const float* c0  = (const float*)d_in[2];
    const float* Wih = (const float*)d_in[3];
    const float* Whh = (const float*)d_in[4];
    const float* bih = (const float*)d_in[5];
    const float* bhh = (const float*)d_in[6];
    float* out = (float*)d_out;

    char* ws = (char*)d_ws;
    size_t off = 0;
    auto alloc = [&](size_t bytes) -> char* {
        char* p = ws + off; off += (bytes + 255) & ~(size_t)255; return p;
    };
    unsigned short* Wcat = (unsigned short*)alloc((size_t)4 * 256 * 65536 * 2);  // 128 MiB
    unsigned short* Xhi  = (unsigned short*)alloc(65536 * 2);
    unsigned short* Xlo  = (unsigned short*)alloc(65536 * 2);
    unsigned short* Hhi  = (unsigned short*)alloc((size_t)2 * 4 * 65536 * 2);
    unsigned short* Hlo  = (unsigned short*)alloc((size_t)2 * 4 * 65536 * 2);
    unsigned*       sync = (unsigned*)alloc(256);

    hipMemsetAsync(sync, 0, 256, stream);
    prep_w<<<16384, 256, 0, stream>>>(Wih, Whh, Wcat);
    prep_state<<<1280, 256, 0, stream>>>(x, h0, Xhi, Xlo, Hhi, Hlo);

    void* kargs[] = { (void*)&Wcat, (void*)&Xhi, (void*)&Xlo, (void*)&Hhi, (void*)&Hlo,
                      (void*)&c0, (void*)&bih, (void*)&bhh, (void*)&out, (void*)&sync };
    hipLaunchCooperativeKernel((void*)lstm_fused, dim3(256), dim3(512), kargs, 0, stream);

    (void)in_sizes; (void)n_in; (void)out_size; (void)ws_size;
}

// Round 6
// 8103.496 us; speedup vs baseline: 1.3043x; 1.0989x over previous
//
#include <hip/hip_runtime.h>
#include <hip/hip_bf16.h>
#include <stdint.h>

// Problem constants (fixed by the reference): B=64, L=4, H=1024, T=128.
#define NB   64
#define NH   1024
#define NL   4
#define NT   128

using bf16x8 = __attribute__((ext_vector_type(8))) short;  // 8 bf16 in 4 VGPRs
using f32x4  = __attribute__((ext_vector_type(4))) float;

// Split fp32 v into hi+lo bf16 (RNE). v ~= hi + lo with residual ~2^-17 * |v|.
__device__ __forceinline__ void split_bf16(float v, unsigned short& hi, unsigned short& lo) {
    unsigned u = __float_as_uint(v);
    unsigned short h = (unsigned short)((u + 0x7FFFu + ((u >> 16) & 1u)) >> 16);
    float hf = __uint_as_float((unsigned)h << 16);
    float r  = v - hf;
    unsigned ur = __float_as_uint(r);
    unsigned short l = (unsigned short)((ur + 0x7FFFu + ((ur >> 16) & 1u)) >> 16);
    hi = h; lo = l;
}

// A-swizzle for a (64 x 1024) activation: element (m,k) at
// ((k>>5)*4 + (m>>4))*512 + ((m&15) + ((k>>3)&3)*16)*8 + (k&7).   [verified R1-R3]
__device__ __forceinline__ size_t aswz(int m, int k) {
    return ((size_t)((k >> 5) * 4 + (m >> 4)) * 64 + ((m & 15) + ((k >> 3) & 3) * 16)) * 8
           + (k & 7);
}

#define HOFF(p, l) (((size_t)(p) * 4 + (l)) * 65536)

// ---------------------------------------------------------------------------
// prep_w (VERBATIM R3): fp32 W -> swizzled hi/lo bf16 stream.
// Wcat[l][bj][phase 16][tile 4][part 2][512]; tile = 2*kh + (kcl&1),
// phase = kcl>>1. Per-cell-per-block stream = 16 phases x 8 KB, sequential.
// ---------------------------------------------------------------------------
__global__ __launch_bounds__(256)
void prep_w(const float* __restrict__ Wih, const float* __restrict__ Whh,
            unsigned short* __restrict__ Wcat)
{
    int gid = blockIdx.x * 256 + threadIdx.x;      // (l, kc, nt, L)
    int L  = gid & 63;
    int nt = (gid >> 6) & 255;
    int kc = (gid >> 14) & 63;
    int l  = gid >> 20;                            // 0..3
    int np = nt * 16 + (L & 15);                   // n' in [0,4096)
    int g  = np & 3, j = np >> 2;
    int n  = g * 1024 + j;                         // original gate row
    int k0 = kc * 32 + (L >> 4) * 8;               // k in [0,2048)
    const float* src = (k0 < 1024)
        ? (Wih + ((size_t)l * 4096 + n) * 1024 + k0)
        : (Whh + ((size_t)l * 4096 + n) * 1024 + (k0 - 1024));
    float4 s0 = *(const float4*)(src);
    float4 s1 = *(const float4*)(src + 4);
    float sv[8] = {s0.x, s0.y, s0.z, s0.w, s1.x, s1.y, s1.z, s1.w};
    unsigned short hb[8], lb[8];
#pragma unroll
    for (int e = 0; e < 8; ++e) split_bf16(sv[e], hb[e], lb[e]);
    int kh = kc >> 5, kcl = kc & 31;
    int pph = kcl >> 1, tile = 2 * kh + (kcl & 1);
    size_t slotbase = ((size_t)(l * 256 + nt) * 16 + pph) * 4096;
    size_t dsthi = slotbase + (size_t)tile * 1024 + (size_t)L * 8;
    *(ushort4*)&Wcat[dsthi]       = make_ushort4(hb[0], hb[1], hb[2], hb[3]);
    *(ushort4*)&Wcat[dsthi + 4]   = make_ushort4(hb[4], hb[5], hb[6], hb[7]);
    *(ushort4*)&Wcat[dsthi + 512] = make_ushort4(lb[0], lb[1], lb[2], lb[3]);
    *(ushort4*)&Wcat[dsthi + 516] = make_ushort4(lb[4], lb[5], lb[6], lb[7]);
}

// ---------------------------------------------------------------------------
// prep_state (VERBATIM R3)
// ---------------------------------------------------------------------------
__global__ __launch_bounds__(256)
void prep_state(const float* __restrict__ x, const float* __restrict__ h0,
                unsigned short* __restrict__ Xhi, unsigned short* __restrict__ Xlo,
                unsigned short* __restrict__ Hhi, unsigned short* __restrict__ Hlo)
{
    int gid = blockIdx.x * 256 + threadIdx.x;
    if (gid >= 5 * 65536) return;
    int buf = gid >> 16;
    int e = gid & 65535;
    int b = e >> 10, jg = e & 1023;
    float v = (buf == 0) ? x[e] : h0[(size_t)(buf - 1) * 65536 + e];
    size_t idx = aswz(b, jg);
    unsigned short hh, hl; split_bf16(v, hh, hl);
    if (buf == 0) { Xhi[idx] = hh; Xlo[idx] = hl; }
    else {
        Hhi[(size_t)(buf - 1) * 65536 + idx] = hh;
        Hlo[(size_t)(buf - 1) * 65536 + idx] = hl;
    }
}

// ---------------------------------------------------------------------------
// lstm_fused R9: R8 pipeline + COHERENCE RESTRUCTURE.
// Traffic audit: per cell the grid requests ~164 MB (W 32 MB once-per-byte +
// A-broadcast 131 MB = 256 blocks x 512 KB); only 18.5 MB/cell comes from
// HBM => ~145 MB/cell from LLC in 17.4 us ~= 8.3 TB/s: LLC-BW-bound.
// Root cause of zero L2 dedup: the R3 barrier executed an agent-scope
// ACQUIRE per block per cell (spinner acquire load + ACQ_REL RMW), each
// emitting buffer_inv sc1 -> 32 staggered L2 wipes per XCD per cell killed
// the shared A fills AND evicted LLC-resident weights (58% weight HBM miss
// despite Wcat 128 MB < LLC 256 MB).
// New protocol (R4's idea minus R4's drain mistake):
//   - fetch_add RELEASE (no acquire side), spin RELAXED, no trailing acquire.
//   - ONE buffer_inv sc1 per block, issued by tid0 right BEFORE its arrival
//     fetch_add, with NO s_waitcnt attached. All invs complete before the
//     flag is set (inv precedes fetch_add in program order; release drains
//     it; flag is stored only after all 256 arrivals), so every A-load of
//     cell u+1 starts from a clean L2, fills once per XCD, 31 blocks hit.
//   - Stale-line safety with the existing double-buffer: any A line filled
//     during cell u is killed at the u->u+1 barrier; all fills during u+1
//     observe LLC-current h (h-stores are agent write-through + release
//     before flag). No dirty-line loss: h AND out stores are agent-scope
//     atomic stores (write-through); kernel has no other global stores.
// Everything else verbatim R8 (sched_barrier-pinned 4-deep A / 6-deep B
// register pipeline, no LDS ring, no intra-cell barriers).
// ---------------------------------------------------------------------------

#define AISSUE(AV, pp) do {                                                   \
    const unsigned short* _ab = Ah + (size_t)(pp) * 4096 + alane;             \
    const unsigned short* _lb = Al + (size_t)(pp) * 4096 + alane;             \
    AV[0] = *(const bf16x8*)(_ab);                                            \
    AV[1] = *(const bf16x8*)(_lb);                                            \
    AV[2] = *(const bf16x8*)(_ab + 2048);                                     \
    AV[3] = *(const bf16x8*)(_lb + 2048);                                     \
} while (0)

#define BISSUE(BV, pp, stream) do {                                           \
    const unsigned short* _bb = (stream) + (size_t)(pp) * 4096 + blane;       \
    BV[0] = *(const bf16x8*)(_bb);            /* bh0 */                       \
    BV[1] = *(const bf16x8*)(_bb + 512);      /* bl0 */                       \
    BV[2] = *(const bf16x8*)(_bb + 1024);     /* bh1 */                       \
    BV[3] = *(const bf16x8*)(_bb + 1536);     /* bl1 */                       \
} while (0)

// Phase p: consume A name AC (= av[p&3]) and B name BC (= bw[p&7]);
// reload AC with A set p+4 (p<=11); load B into BN (= bw[(p+6)&7]).
#define PHASE(p, AC, BC, BN) do {                                             \
    acc0 = __builtin_amdgcn_mfma_f32_16x16x32_bf16(AC[0], BC[0], acc0, 0, 0, 0); \
    acc1 = __builtin_amdgcn_mfma_f32_16x16x32_bf16(AC[1], BC[0], acc1, 0, 0, 0); \
    acc2 = __builtin_amdgcn_mfma_f32_16x16x32_bf16(AC[0], BC[1], acc2, 0, 0, 0); \
    acc0 = __builtin_amdgcn_mfma_f32_16x16x32_bf16(AC[2], BC[2], acc0, 0, 0, 0); \
    acc1 = __builtin_amdgcn_mfma_f32_16x16x32_bf16(AC[3], BC[2], acc1, 0, 0, 0); \
    acc2 = __builtin_amdgcn_mfma_f32_16x16x32_bf16(AC[2], BC[3], acc2, 0, 0, 0); \
    if ((p) <= 11) AISSUE(AC, (p) + 4);                                       \
    if ((p) <= 9)  BISSUE(BN, (p) + 6, wsrc);                                 \
    else           BISSUE(BN, (p) - 10, wnext);                               \
    __builtin_amdgcn_sched_barrier(0);                                        \
} while (0)

__global__ __launch_bounds__(512, 2)
void lstm_fused(const unsigned short* __restrict__ Wcat,
                const unsigned short* __restrict__ Xhi, const unsigned short* __restrict__ Xlo,
                unsigned short* __restrict__ Hhi, unsigned short* __restrict__ Hlo,
                const float* __restrict__ c0,
                const float* __restrict__ bih, const float* __restrict__ bhh,
                float* __restrict__ out, unsigned* __restrict__ sync)
{
    __shared__ __align__(16) float Gs[2560];                 // 8 tiles x 16 x 20 (pad)
    __shared__ __align__(16) float4 cLd[4][64];              // c state (block-private)
    __shared__ float bcs[64];                                // combined bias

    const int tid = threadIdx.x;
    const int L = tid & 63;
    const int w = tid >> 6;          // 0..7
    const int q = w & 3;             // M-quarter
    const int kh = w >> 2;           // K-half: 0 = input, 1 = recurrent
    const int bj = blockIdx.x;       // n'-tile
    const size_t alane = (size_t)q * 512 + (size_t)L * 8;
    const size_t blane = (size_t)kh * 2048 + (size_t)L * 8;
    unsigned* cnt  = sync;
    unsigned* flag = sync + 32;

    // ---- one-time init: bias + c into LDS (wave0 only; wave0 consumes) ----
    if (tid < 64) {
        int li = tid >> 4, i = tid & 15;
        int jj = bj * 4 + (i >> 2), g = i & 3;
        bcs[tid] = bih[li * 4096 + g * 1024 + jj] + bhh[li * 4096 + g * 1024 + jj];
#pragma unroll
        for (int li2 = 0; li2 < 4; ++li2) {
            const float* cs = c0 + (size_t)li2 * 65536 + (size_t)tid * 1024 + bj * 4;
            cLd[li2][tid] = make_float4(cs[0], cs[1], cs[2], cs[3]);
        }
    }

    bf16x8 av0[4], av1[4], av2[4], av3[4];
    bf16x8 bw0[4], bw1[4], bw2[4], bw3[4], bw4[4], bw5[4], bw6[4], bw7[4];
    const unsigned short *Ah, *Al, *wsrc, *wnext;

    // ---- pre-loop prologue: B sets 0..5 of cell 0 into bw0..bw5 ----
    {
        wsrc  = Wcat + (size_t)bj * 65536;            // l=0
        wnext = Wcat + ((size_t)1 * 256 + bj) * 65536;
        BISSUE(bw0, 0, wsrc); BISSUE(bw1, 1, wsrc); BISSUE(bw2, 2, wsrc);
        BISSUE(bw3, 3, wsrc); BISSUE(bw4, 4, wsrc); BISSUE(bw5, 5, wsrc);
        __builtin_amdgcn_sched_barrier(0);
    }

#pragma unroll 1
    for (int u = 0; u < NT * NL; ++u) {
        const int t = u >> 2, l = u & 3;
        const int pr = t & 1, pw = pr ^ 1;

        // ---- grid barrier: release-only + pre-arrival cache invalidate ----
        if (u) {
            if (tid == 0) {
                // Clean this CU's L1 + XCD's L2 of last cell's A lines (and
                // everything else). NO waitcnt here: the release fetch_add
                // below orders it, and the flag is only set after all 256
                // arrivals -> every inv is complete before any cell-u A-load.
                asm volatile("buffer_inv sc1" ::: "memory");
                unsigned old = __hip_atomic_fetch_add(cnt, 1u, __ATOMIC_RELEASE,
                                                      __HIP_MEMORY_SCOPE_AGENT);
                if (old == 256u * (unsigned)u - 1u) {
                    __hip_atomic_store(flag, (unsigned)u, __ATOMIC_RELEASE,
                                       __HIP_MEMORY_SCOPE_AGENT);
                } else {
                    while (__hip_atomic_load(flag, __ATOMIC_RELAXED,
                                             __HIP_MEMORY_SCOPE_AGENT) < (unsigned)u)
                        __builtin_amdgcn_s_sleep(2);
                }
            }
            asm volatile("s_barrier" ::: "memory");
        }

        // ---- per-cell pointers ----
        {
            const unsigned short *AIh, *AIl;
            if (l == 0) {
                if (t == 0) { AIh = Xhi; AIl = Xlo; }
                else        { AIh = Hhi + HOFF(pr, 3); AIl = Hlo + HOFF(pr, 3); }
            } else          { AIh = Hhi + HOFF(pw, l - 1); AIl = Hlo + HOFF(pw, l - 1); }
            Ah = kh ? (Hhi + HOFF(pr, l)) : AIh;
            Al = kh ? (Hlo + HOFF(pr, l)) : AIl;
            wsrc  = Wcat + ((size_t)l * 256 + bj) * 65536;
            wnext = Wcat + ((size_t)((l + 1) & 3) * 256 + bj) * 65536;
        }

        // ---- A burst: sets 0..3 of this cell (h just became visible) ----
        AISSUE(av0, 0); AISSUE(av1, 1); AISSUE(av2, 2); AISSUE(av3, 3);
        __builtin_amdgcn_sched_barrier(0);

        f32x4 acc0 = {0.f, 0.f, 0.f, 0.f};
        f32x4 acc1 = {0.f, 0.f, 0.f, 0.f};
        f32x4 acc2 = {0.f, 0.f, 0.f, 0.f};

        PHASE( 0, av0, bw0, bw6);  PHASE( 1, av1, bw1, bw7);
        PHASE( 2, av2, bw2, bw0);  PHASE( 3, av3, bw3, bw1);
        PHASE( 4, av0, bw4, bw2);  PHASE( 5, av1, bw5, bw3);
        PHASE( 6, av2, bw6, bw4);  PHASE( 7, av3, bw7, bw5);
        PHASE( 8, av0, bw0, bw6);  PHASE( 9, av1, bw1, bw7);
        PHASE(10, av2, bw2, bw0);  PHASE(11, av3, bw3, bw1);
        PHASE(12, av0, bw4, bw2);  PHASE(13, av1, bw5, bw3);
        PHASE(14, av2, bw6, bw4);  PHASE(15, av3, bw7, bw5);

        // ---- scatter partials: tile = kh*4+q; lane holds D[mq*4+r][nl] ----
        {
            f32x4 avv = (acc0 + acc1) + acc2;
            const int mq = L >> 4, nl = L & 15;
            float* gw = &Gs[(kh * 4 + q) * 320 + nl];
#pragma unroll
            for (int r = 0; r < 4; ++r) gw[(mq * 4 + r) * 20] = avv[r];
        }
        asm volatile("s_waitcnt lgkmcnt(0)\n\ts_barrier" ::: "memory");

        // ---- epilogue: wave0, one batch row each, 4 h-dims (R3-verified) ----
        if (tid < 64) {
            const int bl = tid, qq = bl >> 4, ml = bl & 15;
            float4 cv = cLd[l][bl];
            float ca[4] = {cv.x, cv.y, cv.z, cv.w};
            float hv[4];
            ushort4 h_hi, h_lo;
#pragma unroll
            for (int jl = 0; jl < 4; ++jl) {
                const int base0 = (qq * 16 + ml) * 20 + jl * 4;
                float4 g0 = *(const float4*)&Gs[base0];
                float4 g1 = *(const float4*)&Gs[base0 + 1280];
                float4 bb = *(const float4*)&bcs[l * 16 + jl * 4];
                float gi = g0.x + g1.x + bb.x;
                float gf = g0.y + g1.y + bb.y;
                float gg = g0.z + g1.z + bb.z;
                float go = g0.w + g1.w + bb.w;
                float si = 1.f / (1.f + __expf(-gi));
                float sf = 1.f / (1.f + __expf(-gf));
                float so = 1.f / (1.f + __expf(-go));
                float tg = 1.f - 2.f / (__expf(2.f * gg) + 1.f);
                float cn = sf * ca[jl] + si * tg;
                ca[jl] = cn;
                float tc = 1.f - 2.f / (__expf(2.f * cn) + 1.f);
                hv[jl] = so * tc;
                unsigned short hh, hl; split_bf16(hv[jl], hh, hl);
                ((unsigned short*)&h_hi)[jl] = hh;
                ((unsigned short*)&h_lo)[jl] = hl;
            }
            cLd[l][bl] = make_float4(ca[0], ca[1], ca[2], ca[3]);
            size_t hidx = aswz(bl, bj * 4);
            union { ushort4 v; unsigned long long u; } ch, cl2;
            ch.v = h_hi; cl2.v = h_lo;
            __hip_atomic_store((unsigned long long*)(Hhi + HOFF(pw, l) + hidx), ch.u,
                               __ATOMIC_RELAXED, __HIP_MEMORY_SCOPE_AGENT);
            __hip_atomic_store((unsigned long long*)(Hlo + HOFF(pw, l) + hidx), cl2.u,
                               __ATOMIC_RELAXED, __HIP_MEMORY_SCOPE_AGENT);
            if (l == 3) {
                // write-through (agent atomic) so a buffer_inv can never drop
                // a dirty out line from L2.
                union { float4 f; unsigned long long uu[2]; } ov;
                ov.f = make_float4(hv[0], hv[1], hv[2], hv[3]);
                unsigned long long* op = (unsigned long long*)
                    &out[(size_t)bl * (NT * NH) + (size_t)t * NH + bj * 4];
                __hip_atomic_store(op,     ov.uu[0], __ATOMIC_RELAXED,
                                   __HIP_MEMORY_SCOPE_AGENT);
                __hip_atomic_store(op + 1, ov.uu[1], __ATOMIC_RELAXED,
                                   __HIP_MEMORY_SCOPE_AGENT);
            }
        }
    }
}

// ---------------------------------------------------------------------------
extern "C" void kernel_launch(void* const* d_in, const int* in_sizes, int n_in,
                              void* d_out, int out_size, void* d_ws, size_t ws_size,
                              hipStream_t stream)
{
    const float* x   = (const float*)d_in[0];
    const float* h0  = (const float*)d_in[1];
    const float* c0  = (const float*)d_in[2];
    const float* Wih = (const float*)d_in[3];
    const float* Whh = (const float*)d_in[4];
    const float* bih = (const float*)d_in[5];
    const float* bhh = (const float*)d_in[6];
    float* out = (float*)d_out;

    char* ws = (char*)d_ws;
    size_t off = 0;
    auto alloc = [&](size_t bytes) -> char* {
        char* p = ws + off; off += (bytes + 255) & ~(size_t)255; return p;
    };
    unsigned short* Wcat = (unsigned short*)alloc((size_t)4 * 256 * 65536 * 2);  // 128 MiB
    unsigned short* Xhi  = (unsigned short*)alloc(65536 * 2);
    unsigned short* Xlo  = (unsigned short*)alloc(65536 * 2);
    unsigned short* Hhi  = (unsigned short*)alloc((size_t)2 * 4 * 65536 * 2);
    unsigned short* Hlo  = (unsigned short*)alloc((size_t)2 * 4 * 65536 * 2);
    unsigned*       sync = (unsigned*)alloc(256);

    hipMemsetAsync(sync, 0, 256, stream);
    prep_w<<<16384, 256, 0, stream>>>(Wih, Whh, Wcat);
    prep_state<<<1280, 256, 0, stream>>>(x, h0, Xhi, Xlo, Hhi, Hlo);

    void* kargs[] = { (void*)&Wcat, (void*)&Xhi, (void*)&Xlo, (void*)&Hhi, (void*)&Hlo,
                      (void*)&c0, (void*)&bih, (void*)&bhh, (void*)&out, (void*)&sync };
    hipLaunchCooperativeKernel((void*)lstm_fused, dim3(256), dim3(512), kargs, 0, stream);

    (void)in_sizes; (void)n_in; (void)out_size; (void)ws_size;
}

// Round 7
// 7860.875 us; speedup vs baseline: 1.3446x; 1.0309x over previous
//
#include <hip/hip_runtime.h>
#include <hip/hip_bf16.h>
#include <stdint.h>

// Problem constants (fixed by the reference): B=64, L=4, H=1024, T=128.
#define NB   64
#define NH   1024
#define NL   4
#define NT   128

using bf16x8 = __attribute__((ext_vector_type(8))) short;  // 8 bf16 in 4 VGPRs
using f32x4  = __attribute__((ext_vector_type(4))) float;

// Split fp32 v into hi+lo bf16 (RNE). v ~= hi + lo with residual ~2^-17 * |v|.
__device__ __forceinline__ void split_bf16(float v, unsigned short& hi, unsigned short& lo) {
    unsigned u = __float_as_uint(v);
    unsigned short h = (unsigned short)((u + 0x7FFFu + ((u >> 16) & 1u)) >> 16);
    float hf = __uint_as_float((unsigned)h << 16);
    float r  = v - hf;
    unsigned ur = __float_as_uint(r);
    unsigned short l = (unsigned short)((ur + 0x7FFFu + ((ur >> 16) & 1u)) >> 16);
    hi = h; lo = l;
}

// A-swizzle for a (64 x 1024) activation: element (m,k) at
// ((k>>5)*4 + (m>>4))*512 + ((m&15) + ((k>>3)&3)*16)*8 + (k&7).   [verified R1-R3]
__device__ __forceinline__ size_t aswz(int m, int k) {
    return ((size_t)((k >> 5) * 4 + (m >> 4)) * 64 + ((m & 15) + ((k >> 3) & 3) * 16)) * 8
           + (k & 7);
}

#define HOFF(p, l) (((size_t)(p) * 4 + (l)) * 65536)

// ---------------------------------------------------------------------------
// prep_w (VERBATIM R3): fp32 W -> swizzled hi/lo bf16 stream.
// Wcat[l][bj][phase 16][tile 4][part 2][512]; tile = 2*kh + (kcl&1),
// phase = kcl>>1. Per-cell-per-block stream = 16 phases x 8 KB, sequential.
// ---------------------------------------------------------------------------
__global__ __launch_bounds__(256)
void prep_w(const float* __restrict__ Wih, const float* __restrict__ Whh,
            unsigned short* __restrict__ Wcat)
{
    int gid = blockIdx.x * 256 + threadIdx.x;      // (l, kc, nt, L)
    int L  = gid & 63;
    int nt = (gid >> 6) & 255;
    int kc = (gid >> 14) & 63;
    int l  = gid >> 20;                            // 0..3
    int np = nt * 16 + (L & 15);                   // n' in [0,4096)
    int g  = np & 3, j = np >> 2;
    int n  = g * 1024 + j;                         // original gate row
    int k0 = kc * 32 + (L >> 4) * 8;               // k in [0,2048)
    const float* src = (k0 < 1024)
        ? (Wih + ((size_t)l * 4096 + n) * 1024 + k0)
        : (Whh + ((size_t)l * 4096 + n) * 1024 + (k0 - 1024));
    float4 s0 = *(const float4*)(src);
    float4 s1 = *(const float4*)(src + 4);
    float sv[8] = {s0.x, s0.y, s0.z, s0.w, s1.x, s1.y, s1.z, s1.w};
    unsigned short hb[8], lb[8];
#pragma unroll
    for (int e = 0; e < 8; ++e) split_bf16(sv[e], hb[e], lb[e]);
    int kh = kc >> 5, kcl = kc & 31;
    int pph = kcl >> 1, tile = 2 * kh + (kcl & 1);
    size_t slotbase = ((size_t)(l * 256 + nt) * 16 + pph) * 4096;
    size_t dsthi = slotbase + (size_t)tile * 1024 + (size_t)L * 8;
    *(ushort4*)&Wcat[dsthi]       = make_ushort4(hb[0], hb[1], hb[2], hb[3]);
    *(ushort4*)&Wcat[dsthi + 4]   = make_ushort4(hb[4], hb[5], hb[6], hb[7]);
    *(ushort4*)&Wcat[dsthi + 512] = make_ushort4(lb[0], lb[1], lb[2], lb[3]);
    *(ushort4*)&Wcat[dsthi + 516] = make_ushort4(lb[4], lb[5], lb[6], lb[7]);
}

// ---------------------------------------------------------------------------
// prep_state (VERBATIM R3)
// ---------------------------------------------------------------------------
__global__ __launch_bounds__(256)
void prep_state(const float* __restrict__ x, const float* __restrict__ h0,
                unsigned short* __restrict__ Xhi, unsigned short* __restrict__ Xlo,
                unsigned short* __restrict__ Hhi, unsigned short* __restrict__ Hlo)
{
    int gid = blockIdx.x * 256 + threadIdx.x;
    if (gid >= 5 * 65536) return;
    int buf = gid >> 16;
    int e = gid & 65535;
    int b = e >> 10, jg = e & 1023;
    float v = (buf == 0) ? x[e] : h0[(size_t)(buf - 1) * 65536 + e];
    size_t idx = aswz(b, jg);
    unsigned short hh, hl; split_bf16(v, hh, hl);
    if (buf == 0) { Xhi[idx] = hh; Xlo[idx] = hl; }
    else {
        Hhi[(size_t)(buf - 1) * 65536 + idx] = hh;
        Hlo[(size_t)(buf - 1) * 65536 + idx] = hl;
    }
}

// ---------------------------------------------------------------------------
// lstm_fused R10: R9 + HIERARCHICAL ARRIVAL TREE.
// R9's release-only barrier + pre-arrival inv gained 9%; remaining serial
// term: 256 fetch_adds on ONE LLC line per cell (~10-20 ns each serialized
// ~= 2.5-5 us/cell). Now: 8 group counters (64 B apart; block bj arrives at
// group bj&7) -> last-of-32 bumps a root counter -> last-of-8 stores flag.
// Serialization drops 256 -> 32-per-line (8 lines in parallel) + 8 on root.
// Release chain preserved: tid0's group-RMW (REL) orders its h-stores; the
// leader's root-RMW (REL) orders its group-RMW; flag store (REL) orders the
// root-RMW -> flag==u still implies all 256 blocks' h at LLC. Spin stays
// tid0-only + post-spin s_barrier broadcast (s_barrier does NOT drain vmcnt,
// so the other 7 waves' B-prefetches stay in flight across the barrier).
// Everything else verbatim R9 (sched_barrier-pinned 4-deep A / 6-deep B
// register pipeline, no LDS ring, no intra-cell barriers, single inv/block).
// ---------------------------------------------------------------------------

#define AISSUE(AV, pp) do {                                                   \
    const unsigned short* _ab = Ah + (size_t)(pp) * 4096 + alane;             \
    const unsigned short* _lb = Al + (size_t)(pp) * 4096 + alane;             \
    AV[0] = *(const bf16x8*)(_ab);                                            \
    AV[1] = *(const bf16x8*)(_lb);                                            \
    AV[2] = *(const bf16x8*)(_ab + 2048);                                     \
    AV[3] = *(const bf16x8*)(_lb + 2048);                                     \
} while (0)

#define BISSUE(BV, pp, stream) do {                                           \
    const unsigned short* _bb = (stream) + (size_t)(pp) * 4096 + blane;       \
    BV[0] = *(const bf16x8*)(_bb);            /* bh0 */                       \
    BV[1] = *(const bf16x8*)(_bb + 512);      /* bl0 */                       \
    BV[2] = *(const bf16x8*)(_bb + 1024);     /* bh1 */                       \
    BV[3] = *(const bf16x8*)(_bb + 1536);     /* bl1 */                       \
} while (0)

// Phase p: consume A name AC (= av[p&3]) and B name BC (= bw[p&7]);
// reload AC with A set p+4 (p<=11); load B into BN (= bw[(p+6)&7]).
#define PHASE(p, AC, BC, BN) do {                                             \
    acc0 = __builtin_amdgcn_mfma_f32_16x16x32_bf16(AC[0], BC[0], acc0, 0, 0, 0); \
    acc1 = __builtin_amdgcn_mfma_f32_16x16x32_bf16(AC[1], BC[0], acc1, 0, 0, 0); \
    acc2 = __builtin_amdgcn_mfma_f32_16x16x32_bf16(AC[0], BC[1], acc2, 0, 0, 0); \
    acc0 = __builtin_amdgcn_mfma_f32_16x16x32_bf16(AC[2], BC[2], acc0, 0, 0, 0); \
    acc1 = __builtin_amdgcn_mfma_f32_16x16x32_bf16(AC[3], BC[2], acc1, 0, 0, 0); \
    acc2 = __builtin_amdgcn_mfma_f32_16x16x32_bf16(AC[2], BC[3], acc2, 0, 0, 0); \
    if ((p) <= 11) AISSUE(AC, (p) + 4);                                       \
    if ((p) <= 9)  BISSUE(BN, (p) + 6, wsrc);                                 \
    else           BISSUE(BN, (p) - 10, wnext);                               \
    __builtin_amdgcn_sched_barrier(0);                                        \
} while (0)

__global__ __launch_bounds__(512, 2)
void lstm_fused(const unsigned short* __restrict__ Wcat,
                const unsigned short* __restrict__ Xhi, const unsigned short* __restrict__ Xlo,
                unsigned short* __restrict__ Hhi, unsigned short* __restrict__ Hlo,
                const float* __restrict__ c0,
                const float* __restrict__ bih, const float* __restrict__ bhh,
                float* __restrict__ out, unsigned* __restrict__ sync)
{
    __shared__ __align__(16) float Gs[2560];                 // 8 tiles x 16 x 20 (pad)
    __shared__ __align__(16) float4 cLd[4][64];              // c state (block-private)
    __shared__ float bcs[64];                                // combined bias

    const int tid = threadIdx.x;
    const int L = tid & 63;
    const int w = tid >> 6;          // 0..7
    const int q = w & 3;             // M-quarter
    const int kh = w >> 2;           // K-half: 0 = input, 1 = recurrent
    const int bj = blockIdx.x;       // n'-tile
    const size_t alane = (size_t)q * 512 + (size_t)L * 8;
    const size_t blane = (size_t)kh * 2048 + (size_t)L * 8;

    // ---- one-time init: bias + c into LDS (wave0 only; wave0 consumes) ----
    if (tid < 64) {
        int li = tid >> 4, i = tid & 15;
        int jj = bj * 4 + (i >> 2), g = i & 3;
        bcs[tid] = bih[li * 4096 + g * 1024 + jj] + bhh[li * 4096 + g * 1024 + jj];
#pragma unroll
        for (int li2 = 0; li2 < 4; ++li2) {
            const float* cs = c0 + (size_t)li2 * 65536 + (size_t)tid * 1024 + bj * 4;
            cLd[li2][tid] = make_float4(cs[0], cs[1], cs[2], cs[3]);
        }
    }

    bf16x8 av0[4], av1[4], av2[4], av3[4];
    bf16x8 bw0[4], bw1[4], bw2[4], bw3[4], bw4[4], bw5[4], bw6[4], bw7[4];
    const unsigned short *Ah, *Al, *wsrc, *wnext;

    // ---- pre-loop prologue: B sets 0..5 of cell 0 into bw0..bw5 ----
    {
        wsrc  = Wcat + (size_t)bj * 65536;            // l=0
        wnext = Wcat + ((size_t)1 * 256 + bj) * 65536;
        BISSUE(bw0, 0, wsrc); BISSUE(bw1, 1, wsrc); BISSUE(bw2, 2, wsrc);
        BISSUE(bw3, 3, wsrc); BISSUE(bw4, 4, wsrc); BISSUE(bw5, 5, wsrc);
        __builtin_amdgcn_sched_barrier(0);
    }

#pragma unroll 1
    for (int u = 0; u < NT * NL; ++u) {
        const int t = u >> 2, l = u & 3;
        const int pr = t & 1, pw = pr ^ 1;

        // ---- grid barrier: release-only, pre-arrival inv, TREE arrival ----
        if (u) {
            if (tid == 0) {
                // Clean this CU's L1 + XCD L2 of last cell's A lines. No
                // waitcnt attached: the release RMW below orders it, and the
                // flag is only set after all 256 arrivals.
                asm volatile("buffer_inv sc1" ::: "memory");
                unsigned* cg = sync + ((unsigned)bj & 7u) * 16u;   // 64B apart
                unsigned old = __hip_atomic_fetch_add(cg, 1u, __ATOMIC_RELEASE,
                                                      __HIP_MEMORY_SCOPE_AGENT);
                if (old == 32u * (unsigned)u - 1u) {
                    unsigned o2 = __hip_atomic_fetch_add(sync + 128, 1u,
                                                         __ATOMIC_RELEASE,
                                                         __HIP_MEMORY_SCOPE_AGENT);
                    if (o2 == 8u * (unsigned)u - 1u) {
                        __hip_atomic_store(sync + 144, (unsigned)u,
                                           __ATOMIC_RELEASE,
                                           __HIP_MEMORY_SCOPE_AGENT);
                    }
                }
                while (__hip_atomic_load(sync + 144, __ATOMIC_RELAXED,
                                         __HIP_MEMORY_SCOPE_AGENT) < (unsigned)u)
                    __builtin_amdgcn_s_sleep(2);
            }
            asm volatile("s_barrier" ::: "memory");
        }

        // ---- per-cell pointers ----
        {
            const unsigned short *AIh, *AIl;
            if (l == 0) {
                if (t == 0) { AIh = Xhi; AIl = Xlo; }
                else        { AIh = Hhi + HOFF(pr, 3); AIl = Hlo + HOFF(pr, 3); }
            } else          { AIh = Hhi + HOFF(pw, l - 1); AIl = Hlo + HOFF(pw, l - 1); }
            Ah = kh ? (Hhi + HOFF(pr, l)) : AIh;
            Al = kh ? (Hlo + HOFF(pr, l)) : AIl;
            wsrc  = Wcat + ((size_t)l * 256 + bj) * 65536;
            wnext = Wcat + ((size_t)((l + 1) & 3) * 256 + bj) * 65536;
        }

        // ---- A burst: sets 0..3 of this cell (h just became visible) ----
        AISSUE(av0, 0); AISSUE(av1, 1); AISSUE(av2, 2); AISSUE(av3, 3);
        __builtin_amdgcn_sched_barrier(0);

        f32x4 acc0 = {0.f, 0.f, 0.f, 0.f};
        f32x4 acc1 = {0.f, 0.f, 0.f, 0.f};
        f32x4 acc2 = {0.f, 0.f, 0.f, 0.f};

        PHASE( 0, av0, bw0, bw6);  PHASE( 1, av1, bw1, bw7);
        PHASE( 2, av2, bw2, bw0);  PHASE( 3, av3, bw3, bw1);
        PHASE( 4, av0, bw4, bw2);  PHASE( 5, av1, bw5, bw3);
        PHASE( 6, av2, bw6, bw4);  PHASE( 7, av3, bw7, bw5);
        PHASE( 8, av0, bw0, bw6);  PHASE( 9, av1, bw1, bw7);
        PHASE(10, av2, bw2, bw0);  PHASE(11, av3, bw3, bw1);
        PHASE(12, av0, bw4, bw2);  PHASE(13, av1, bw5, bw3);
        PHASE(14, av2, bw6, bw4);  PHASE(15, av3, bw7, bw5);

        // ---- scatter partials: tile = kh*4+q; lane holds D[mq*4+r][nl] ----
        {
            f32x4 avv = (acc0 + acc1) + acc2;
            const int mq = L >> 4, nl = L & 15;
            float* gw = &Gs[(kh * 4 + q) * 320 + nl];
#pragma unroll
            for (int r = 0; r < 4; ++r) gw[(mq * 4 + r) * 20] = avv[r];
        }
        asm volatile("s_waitcnt lgkmcnt(0)\n\ts_barrier" ::: "memory");

        // ---- epilogue: wave0, one batch row each, 4 h-dims (R3-verified) ----
        if (tid < 64) {
            const int bl = tid, qq = bl >> 4, ml = bl & 15;
            float4 cv = cLd[l][bl];
            float ca[4] = {cv.x, cv.y, cv.z, cv.w};
            float hv[4];
            ushort4 h_hi, h_lo;
#pragma unroll
            for (int jl = 0; jl < 4; ++jl) {
                const int base0 = (qq * 16 + ml) * 20 + jl * 4;
                float4 g0 = *(const float4*)&Gs[base0];
                float4 g1 = *(const float4*)&Gs[base0 + 1280];
                float4 bb = *(const float4*)&bcs[l * 16 + jl * 4];
                float gi = g0.x + g1.x + bb.x;
                float gf = g0.y + g1.y + bb.y;
                float gg = g0.z + g1.z + bb.z;
                float go = g0.w + g1.w + bb.w;
                float si = 1.f / (1.f + __expf(-gi));
                float sf = 1.f / (1.f + __expf(-gf));
                float so = 1.f / (1.f + __expf(-go));
                float tg = 1.f - 2.f / (__expf(2.f * gg) + 1.f);
                float cn = sf * ca[jl] + si * tg;
                ca[jl] = cn;
                float tc = 1.f - 2.f / (__expf(2.f * cn) + 1.f);
                hv[jl] = so * tc;
                unsigned short hh, hl; split_bf16(hv[jl], hh, hl);
                ((unsigned short*)&h_hi)[jl] = hh;
                ((unsigned short*)&h_lo)[jl] = hl;
            }
            cLd[l][bl] = make_float4(ca[0], ca[1], ca[2], ca[3]);
            size_t hidx = aswz(bl, bj * 4);
            union { ushort4 v; unsigned long long u; } ch, cl2;
            ch.v = h_hi; cl2.v = h_lo;
            __hip_atomic_store((unsigned long long*)(Hhi + HOFF(pw, l) + hidx), ch.u,
                               __ATOMIC_RELAXED, __HIP_MEMORY_SCOPE_AGENT);
            __hip_atomic_store((unsigned long long*)(Hlo + HOFF(pw, l) + hidx), cl2.u,
                               __ATOMIC_RELAXED, __HIP_MEMORY_SCOPE_AGENT);
            if (l == 3) {
                // write-through (agent atomic) so a buffer_inv can never drop
                // a dirty out line from L2.
                union { float4 f; unsigned long long uu[2]; } ov;
                ov.f = make_float4(hv[0], hv[1], hv[2], hv[3]);
                unsigned long long* op = (unsigned long long*)
                    &out[(size_t)bl * (NT * NH) + (size_t)t * NH + bj * 4];
                __hip_atomic_store(op,     ov.uu[0], __ATOMIC_RELAXED,
                                   __HIP_MEMORY_SCOPE_AGENT);
                __hip_atomic_store(op + 1, ov.uu[1], __ATOMIC_RELAXED,
                                   __HIP_MEMORY_SCOPE_AGENT);
            }
        }
    }
}

// ---------------------------------------------------------------------------
extern "C" void kernel_launch(void* const* d_in, const int* in_sizes, int n_in,
                              void* d_out, int out_size, void* d_ws, size_t ws_size,
                              hipStream_t stream)
{
    const float* x   = (const float*)d_in[0];
    const float* h0  = (const float*)d_in[1];
    const float* c0  = (const float*)d_in[2];
    const float* Wih = (const float*)d_in[3];
    const float* Whh = (const float*)d_in[4];
    const float* bih = (const float*)d_in[5];
    const float* bhh = (const float*)d_in[6];
    float* out = (float*)d_out;

    char* ws = (char*)d_ws;
    size_t off = 0;
    auto alloc = [&](size_t bytes) -> char* {
        char* p = ws + off; off += (bytes + 255) & ~(size_t)255; return p;
    };
    unsigned short* Wcat = (unsigned short*)alloc((size_t)4 * 256 * 65536 * 2);  // 128 MiB
    unsigned short* Xhi  = (unsigned short*)alloc(65536 * 2);
    unsigned short* Xlo  = (unsigned short*)alloc(65536 * 2);
    unsigned short* Hhi  = (unsigned short*)alloc((size_t)2 * 4 * 65536 * 2);
    unsigned short* Hlo  = (unsigned short*)alloc((size_t)2 * 4 * 65536 * 2);
    unsigned*       sync = (unsigned*)alloc(1024);

    hipMemsetAsync(sync, 0, 1024, stream);
    prep_w<<<16384, 256, 0, stream>>>(Wih, Whh, Wcat);
    prep_state<<<1280, 256, 0, stream>>>(x, h0, Xhi, Xlo, Hhi, Hlo);

    void* kargs[] = { (void*)&Wcat, (void*)&Xhi, (void*)&Xlo, (void*)&Hhi, (void*)&Hlo,
                      (void*)&c0, (void*)&bih, (void*)&bhh, (void*)&out, (void*)&sync };
    hipLaunchCooperativeKernel((void*)lstm_fused, dim3(256), dim3(512), kargs, 0, stream);

    (void)in_sizes; (void)n_in; (void)out_size; (void)ws_size;
}